// Round 5
// baseline (460.777 us; speedup 1.0000x reference)
//
#include <hip/hip_runtime.h>
#include <math.h>

#define R_LOG2 13
#define R_BKT  8192      // constraints per bucket (32 KB LDS accumulator)
#define SLICE  16        // blocks per bucket in accumulate phase
#define MAXNB  64        // max buckets supported by fast path
#define PB     512       // partition block size (8 waves)
#define BLK_RECS 8192    // records per partition block

// clang ext-vector types: required by __builtin_nontemporal_load/store
// (HIP_vector_type wrappers are rejected by the builtin).
typedef int      iv4 __attribute__((ext_vector_type(4)));
typedef float    fv4 __attribute__((ext_vector_type(4)));
typedef unsigned uv4 __attribute__((ext_vector_type(4)));

// ============================= fast path =============================

// probs = sigmoid(pred) (float4); zero bucket cursors and out.
__global__ void init_fast(const float4* __restrict__ pred4,
                          float4* __restrict__ probs4,
                          unsigned* __restrict__ cursor,
                          float* __restrict__ out,
                          int n_vars4, int nb) {
    int i = blockIdx.x * blockDim.x + threadIdx.x;
    if (i < n_vars4) {
        float4 p = pred4[i];
        float4 q;
        q.x = 1.0f / (1.0f + expf(-p.x));
        q.y = 1.0f / (1.0f + expf(-p.y));
        q.z = 1.0f / (1.0f + expf(-p.z));
        q.w = 1.0f / (1.0f + expf(-p.w));
        probs4[i] = q;
    }
    if (i < nb) cursor[i] = 0;
    if (i == 0) out[0] = 0.0f;
}

// Phase 1: block counting-sort of 8192 records by bucket (cidx>>13).
// Wave-replicated histogram -> wave-0 shfl scan -> LDS scatter ->
// per-bucket coalesced copy-out.
// Record: {lidx:13 in [31:16] | bf16(val):16}. 4 barriers total.
// hist/lcur layout is [wave][bucket] (stride 64): bank = b%32, so the 64
// lanes of a wave (random buckets) spread ~2-way across banks (free),
// instead of the 16-way conflict of the [bucket][wave] layout
// (bank=(8b+w)%32 -> 4 banks per wave). SQ_LDS_BANK_CONFLICT was 1.4e7.
__global__ __launch_bounds__(PB) void partition_kernel(
        const int* __restrict__ cidx, const int* __restrict__ vidx,
        const float* __restrict__ coeff, const float* __restrict__ probs,
        unsigned* __restrict__ cursor, unsigned* __restrict__ recs,
        int nnz4, int nb, unsigned cap) {
    __shared__ unsigned sorted[BLK_RECS];     // 32 KB
    __shared__ unsigned hist[8 * MAXNB];      // [w*64 + b] 2 KB
    __shared__ unsigned lcur[8 * MAXNB];      // running cursors 2 KB
    __shared__ unsigned bst[MAXNB + 1];       // bucket starts in sorted[]
    __shared__ unsigned gbs[MAXNB];           // reserved global bases

    const int tid  = threadIdx.x;
    const int w    = tid >> 6;                // wave 0..7
    const int lane = tid & 63;

    hist[tid] = 0;                            // 512 counters, 512 threads

    // ---- compute this thread's 16 records ----
    unsigned rw[16];
    unsigned bk[16];
    bool     gv[4];
    const unsigned vbase = blockIdx.x * (BLK_RECS / 4);
    const bool full = (vbase + (BLK_RECS / 4)) <= (unsigned)nnz4;

    if (full) {
        #pragma unroll
        for (int g = 0; g < 4; ++g) {
            unsigned v = vbase + g * PB + (unsigned)tid;
            iv4 c4 = __builtin_nontemporal_load((const iv4*)cidx + v);
            iv4 v4 = __builtin_nontemporal_load((const iv4*)vidx + v);
            fv4 w4 = __builtin_nontemporal_load((const fv4*)coeff + v);
            int   cc[4] = {c4.x, c4.y, c4.z, c4.w};
            float vv[4] = {w4.x * probs[v4.x], w4.y * probs[v4.y],
                           w4.z * probs[v4.z], w4.w * probs[v4.w]};
            #pragma unroll
            for (int j = 0; j < 4; ++j) {
                int k = g * 4 + j;
                unsigned bits = __builtin_bit_cast(unsigned, vv[j]);
                bits += 0x7FFFu + ((bits >> 16) & 1u);     // RNE to bf16
                rw[k] = ((unsigned)(cc[j] & (R_BKT - 1)) << 16) | (bits >> 16);
                bk[k] = (unsigned)cc[j] >> R_LOG2;
            }
            gv[g] = true;
        }
    } else {
        #pragma unroll
        for (int g = 0; g < 4; ++g) {
            unsigned v = vbase + g * PB + (unsigned)tid;
            gv[g] = v < (unsigned)nnz4;
            if (gv[g]) {
                int4   c4 = ((const int4*)cidx)[v];
                int4   v4 = ((const int4*)vidx)[v];
                float4 w4 = ((const float4*)coeff)[v];
                int   cc[4] = {c4.x, c4.y, c4.z, c4.w};
                float vv[4] = {w4.x * probs[v4.x], w4.y * probs[v4.y],
                               w4.z * probs[v4.z], w4.w * probs[v4.w]};
                #pragma unroll
                for (int j = 0; j < 4; ++j) {
                    int k = g * 4 + j;
                    unsigned bits = __builtin_bit_cast(unsigned, vv[j]);
                    bits += 0x7FFFu + ((bits >> 16) & 1u);
                    rw[k] = ((unsigned)(cc[j] & (R_BKT - 1)) << 16) | (bits >> 16);
                    bk[k] = (unsigned)cc[j] >> R_LOG2;
                }
            }
        }
    }
    __syncthreads();

    // ---- pass A: wave-replicated histogram ([w][b] layout) ----
    if (full) {
        #pragma unroll
        for (int k = 0; k < 16; ++k)
            atomicAdd(&hist[(w << 6) + bk[k]], 1u);
    } else {
        #pragma unroll
        for (int g = 0; g < 4; ++g) if (gv[g]) {
            #pragma unroll
            for (int j = 0; j < 4; ++j)
                atomicAdd(&hist[(w << 6) + bk[g * 4 + j]], 1u);
        }
    }
    __syncthreads();

    // ---- wave-0: scan bucket totals, set cursors, reserve global space ----
    if (w == 0) {
        unsigned h[8];
        unsigned cnt = 0;
        if (lane < nb) {
            #pragma unroll
            for (int j = 0; j < 8; ++j) { h[j] = hist[(j << 6) + lane]; cnt += h[j]; }
        }
        unsigned sc = cnt;
        #pragma unroll
        for (int d = 1; d < 64; d <<= 1) {
            unsigned t = __shfl_up(sc, d, 64);
            if (lane >= d) sc += t;
        }
        unsigned excl  = sc - cnt;
        unsigned total = __shfl(sc, nb - 1, 64);
        if (lane < nb) {
            bst[lane] = excl;
            unsigned run = excl;
            #pragma unroll
            for (int j = 0; j < 8; ++j) { lcur[(j << 6) + lane] = run; run += h[j]; }
            gbs[lane] = cnt ? atomicAdd(&cursor[lane], cnt) : 0u;
        }
        if (lane == 0) bst[nb] = total;
    }
    __syncthreads();

    // ---- pass B: scatter into sorted LDS ----
    if (full) {
        #pragma unroll
        for (int k = 0; k < 16; ++k) {
            unsigned pos = atomicAdd(&lcur[(w << 6) + bk[k]], 1u);
            sorted[pos] = rw[k];
        }
    } else {
        #pragma unroll
        for (int g = 0; g < 4; ++g) if (gv[g]) {
            #pragma unroll
            for (int j = 0; j < 4; ++j) {
                int k = g * 4 + j;
                unsigned pos = atomicAdd(&lcur[(w << 6) + bk[k]], 1u);
                sorted[pos] = rw[k];
            }
        }
    }
    __syncthreads();

    // ---- copy-out: wave w handles buckets w, w+8, ... (contiguous both sides) ----
    for (int b = w; b < nb; b += 8) {
        unsigned st = bst[b], en = bst[b + 1], gb = gbs[b];
        unsigned* dst = recs + (size_t)b * cap;
        for (unsigned p = st + (unsigned)lane; p < en; p += 64u) {
            unsigned pos = gb + (p - st);
            if (pos < cap) __builtin_nontemporal_store(sorted[p], &dst[pos]);
        }
    }
}

// Phase 2: block (b,s) accumulates slice s of bucket b into LDS via ds_add,
// vec4 NT record loads, then streams out a per-slice partial copy (NT).
__global__ __launch_bounds__(256) void accum_kernel(
        const unsigned* __restrict__ recs, const unsigned* __restrict__ cursor,
        float* __restrict__ partial, int n_constrs, unsigned cap) {
    __shared__ float acc[R_BKT];
    const int b = blockIdx.x / SLICE;
    const int s = blockIdx.x % SLICE;
    for (int j = threadIdx.x * 4; j < R_BKT; j += blockDim.x * 4)
        *(float4*)(acc + j) = make_float4(0.f, 0.f, 0.f, 0.f);
    __syncthreads();

    unsigned cnt = cursor[b];
    if (cnt > cap) cnt = cap;
    const unsigned* base = recs + (size_t)b * cap;

    unsigned c4 = cnt >> 2;
    unsigned s4 = (unsigned)(((unsigned long long)c4 * s) / SLICE);
    unsigned e4 = (unsigned)(((unsigned long long)c4 * (s + 1)) / SLICE);
    const uv4* b4 = (const uv4*)base;
    #pragma unroll 2
    for (unsigned i = s4 + threadIdx.x; i < e4; i += blockDim.x) {
        uv4 r = __builtin_nontemporal_load(b4 + i);
        unsafeAtomicAdd(&acc[r.x >> 16], __builtin_bit_cast(float, (r.x & 0xFFFFu) << 16));
        unsafeAtomicAdd(&acc[r.y >> 16], __builtin_bit_cast(float, (r.y & 0xFFFFu) << 16));
        unsafeAtomicAdd(&acc[r.z >> 16], __builtin_bit_cast(float, (r.z & 0xFFFFu) << 16));
        unsafeAtomicAdd(&acc[r.w >> 16], __builtin_bit_cast(float, (r.w & 0xFFFFu) << 16));
    }
    if (s == SLICE - 1) {
        for (unsigned i = (c4 << 2) + threadIdx.x; i < cnt; i += blockDim.x) {
            unsigned r = base[i];
            unsafeAtomicAdd(&acc[r >> 16], __builtin_bit_cast(float, (r & 0xFFFFu) << 16));
        }
    }
    __syncthreads();

    const int gb = b * R_BKT;
    float* dst = partial + (size_t)s * n_constrs;
    for (int j = threadIdx.x * 4; j < R_BKT; j += blockDim.x * 4) {
        int g = gb + j;
        if (g < n_constrs) {
            fv4 v = {acc[j], acc[j+1], acc[j+2], acc[j+3]};
            __builtin_nontemporal_store(v, (fv4*)(dst + g));
        }
    }
}

// Phase 3: sum SLICE partials (float4, NT), violation by sense, mean.
__device__ __forceinline__ float viol(float d, int sn) {
    return (sn == 1) ? fmaxf(d, 0.0f)
         : (sn == 2) ? fmaxf(-d, 0.0f)
         : (sn == 3) ? fabsf(d)
         : 0.0f;
}

__global__ void reduce_fast(const float* __restrict__ partial,
                            const float4* __restrict__ rhs4,
                            const int4* __restrict__ sense4,
                            float* __restrict__ out,
                            int n4, float inv_n) {
    int i = blockIdx.x * blockDim.x + threadIdx.x;
    float v = 0.0f;
    if (i < n4) {
        fv4 a = {0.f, 0.f, 0.f, 0.f};
        const fv4* p4 = (const fv4*)partial;
        #pragma unroll
        for (int s = 0; s < SLICE; ++s) {
            fv4 p = __builtin_nontemporal_load(p4 + (size_t)s * n4 + i);
            a.x += p.x; a.y += p.y; a.z += p.z; a.w += p.w;
        }
        float4 r = rhs4[i];
        int4  sn = sense4[i];
        v = viol(a.x - r.x, sn.x) + viol(a.y - r.y, sn.y)
          + viol(a.z - r.z, sn.z) + viol(a.w - r.w, sn.w);
    }
    #pragma unroll
    for (int off = 32; off > 0; off >>= 1)
        v += __shfl_down(v, off, 64);
    __shared__ float wsum[4];
    int lane = threadIdx.x & 63;
    int wid  = threadIdx.x >> 6;
    if (lane == 0) wsum[wid] = v;
    __syncthreads();
    if (threadIdx.x == 0)
        atomicAdd(out, (wsum[0] + wsum[1] + wsum[2] + wsum[3]) * inv_n);
}

// ======================= fallback path (small ws) =======================

__global__ void init_kernel(const float* __restrict__ pred,
                            float* __restrict__ probs,
                            float* __restrict__ ax,
                            float* __restrict__ out,
                            int n_vars, int n_constrs) {
    int i = blockIdx.x * blockDim.x + threadIdx.x;
    if (i < n_vars) probs[i] = 1.0f / (1.0f + expf(-pred[i]));
    if (i < n_constrs) ax[i] = 0.0f;
    if (i == 0) out[0] = 0.0f;
}

__global__ void scatter_kernel(const int* __restrict__ cidx,
                               const int* __restrict__ vidx,
                               const float* __restrict__ coeff,
                               const float* __restrict__ probs,
                               float* __restrict__ ax,
                               int nnz) {
    int i = blockIdx.x * blockDim.x + threadIdx.x;
    long long base = (long long)i * 4;
    if (base + 3 < (long long)nnz) {
        int4   c = ((const int4*)cidx)[i];
        int4   v = ((const int4*)vidx)[i];
        float4 w = ((const float4*)coeff)[i];
        unsafeAtomicAdd(&ax[c.x], w.x * probs[v.x]);
        unsafeAtomicAdd(&ax[c.y], w.y * probs[v.y]);
        unsafeAtomicAdd(&ax[c.z], w.z * probs[v.z]);
        unsafeAtomicAdd(&ax[c.w], w.w * probs[v.w]);
    } else if (base < (long long)nnz) {
        for (long long k = base; k < (long long)nnz; ++k)
            unsafeAtomicAdd(&ax[cidx[k]], coeff[k] * probs[vidx[k]]);
    }
}

__global__ void reduce_kernel(const float* __restrict__ ax,
                              const float* __restrict__ rhs,
                              const int* __restrict__ sense,
                              float* __restrict__ out,
                              int n_constrs, float inv_n) {
    int i = blockIdx.x * blockDim.x + threadIdx.x;
    float v = 0.0f;
    if (i < n_constrs) {
        float d = ax[i] - rhs[i];
        int s = sense[i];
        v = (s == 1) ? fmaxf(d, 0.0f)
          : (s == 2) ? fmaxf(-d, 0.0f)
          : (s == 3) ? fabsf(d)
          : 0.0f;
    }
    #pragma unroll
    for (int off = 32; off > 0; off >>= 1)
        v += __shfl_down(v, off, 64);
    __shared__ float wsum[4];
    int lane = threadIdx.x & 63;
    int wid  = threadIdx.x >> 6;
    if (lane == 0) wsum[wid] = v;
    __syncthreads();
    if (threadIdx.x == 0)
        atomicAdd(out, (wsum[0] + wsum[1] + wsum[2] + wsum[3]) * inv_n);
}

// ============================== launch ==============================

static inline size_t align16(size_t x) { return (x + 15) & ~(size_t)15; }

extern "C" void kernel_launch(void* const* d_in, const int* in_sizes, int n_in,
                              void* d_out, int out_size, void* d_ws, size_t ws_size,
                              hipStream_t stream) {
    const float* pred  = (const float*)d_in[0];
    const int*   cidx  = (const int*)d_in[1];
    const int*   vidx  = (const int*)d_in[2];
    const float* coeff = (const float*)d_in[3];
    const float* rhs   = (const float*)d_in[4];
    const int*   sense = (const int*)d_in[5];

    const int n_vars    = in_sizes[0];
    const int nnz       = in_sizes[1];
    const int n_constrs = in_sizes[4];
    const int B = 256;
    const float inv_n = 1.0f / (float)n_constrs;

    const int nb = (n_constrs + R_BKT - 1) / R_BKT;
    unsigned cap = (unsigned)(((double)nnz * R_BKT / (double)n_constrs) * 1.0625) + 1024;
    cap = (cap + 3u) & ~3u;   // 16B alignment for uint4 loads in accum

    // fast-path workspace layout
    size_t off_probs  = 0;
    size_t off_cursor = align16(off_probs + (size_t)n_vars * 4);
    size_t off_recs   = align16(off_cursor + (size_t)nb * 4);
    size_t off_part   = align16(off_recs + (size_t)nb * cap * 4);
    size_t need_fast  = off_part + (size_t)SLICE * n_constrs * 4;

    bool fast = (ws_size >= need_fast) && (nb <= MAXNB) && ((nnz & 3) == 0)
             && ((n_vars & 3) == 0) && ((n_constrs & 3) == 0);

    if (fast) {
        float*    probs   = (float*)((char*)d_ws + off_probs);
        unsigned* cursor  = (unsigned*)((char*)d_ws + off_cursor);
        unsigned* recs    = (unsigned*)((char*)d_ws + off_recs);
        float*    partial = (float*)((char*)d_ws + off_part);
        float*    out     = (float*)d_out;

        int n_vars4 = n_vars >> 2;
        int init_n  = n_vars4 > nb ? n_vars4 : nb;
        init_fast<<<(init_n + B - 1) / B, B, 0, stream>>>(
            (const float4*)pred, (float4*)probs, cursor, out, n_vars4, nb);

        int nnz4 = nnz >> 2;
        int nblk1 = (nnz4 + (BLK_RECS / 4) - 1) / (BLK_RECS / 4);
        partition_kernel<<<nblk1, PB, 0, stream>>>(
            cidx, vidx, coeff, probs, cursor, recs, nnz4, nb, cap);

        accum_kernel<<<nb * SLICE, B, 0, stream>>>(
            recs, cursor, partial, n_constrs, cap);

        int n4 = n_constrs >> 2;
        reduce_fast<<<(n4 + B - 1) / B, B, 0, stream>>>(
            partial, (const float4*)rhs, (const int4*)sense,
            out, n4, inv_n);
    } else {
        float* probs = (float*)d_ws;
        float* ax    = probs + n_vars;
        float* out   = (float*)d_out;

        int init_n = n_vars > n_constrs ? n_vars : n_constrs;
        init_kernel<<<(init_n + B - 1) / B, B, 0, stream>>>(
            pred, probs, ax, out, n_vars, n_constrs);

        int n_vec_threads = (nnz + 3) / 4;
        scatter_kernel<<<(n_vec_threads + B - 1) / B, B, 0, stream>>>(
            cidx, vidx, coeff, probs, ax, nnz);

        reduce_kernel<<<(n_constrs + B - 1) / B, B, 0, stream>>>(
            ax, rhs, sense, out, n_constrs, inv_n);
    }
}

// Round 7
// 447.399 us; speedup vs baseline: 1.0299x; 1.0299x over previous
//
#include <hip/hip_runtime.h>
#include <math.h>

#define R_LOG2 13
#define R_BKT  8192      // constraints per bucket (32 KB LDS accumulator)
#define SLICE  8         // blocks per bucket in accumulate phase
#define MAXNB  64        // max buckets supported by fast path
#define PB     512       // partition block size (8 waves)
#define BLK_RECS 8192    // records per partition block

// clang ext-vector types: required by __builtin_nontemporal_load/store
// (HIP_vector_type wrappers are rejected by the builtin).
typedef int      iv4 __attribute__((ext_vector_type(4)));
typedef float    fv4 __attribute__((ext_vector_type(4)));
typedef unsigned uv4 __attribute__((ext_vector_type(4)));

__device__ __forceinline__ unsigned short f32_to_bf16_rne(float f) {
    unsigned b = __builtin_bit_cast(unsigned, f);
    b += 0x7FFFu + ((b >> 16) & 1u);
    return (unsigned short)(b >> 16);
}

// ============================= fast path =============================

// probs = bf16(sigmoid(pred)) — 2 MB table stays L2-resident under the
// streaming traffic (4 MB f32 table contended with the 4 MB/XCD L2).
// Also zeroes ax (atomic accumulation target), cursors, out.
__global__ void init_fast(const float4* __restrict__ pred4,
                          ushort4* __restrict__ probs4,
                          float4* __restrict__ ax4,
                          unsigned* __restrict__ cursor,
                          float* __restrict__ out,
                          int n_vars4, int nc4, int nb) {
    int i = blockIdx.x * blockDim.x + threadIdx.x;
    if (i < n_vars4) {
        float4 p = pred4[i];
        ushort4 q;
        q.x = f32_to_bf16_rne(1.0f / (1.0f + expf(-p.x)));
        q.y = f32_to_bf16_rne(1.0f / (1.0f + expf(-p.y)));
        q.z = f32_to_bf16_rne(1.0f / (1.0f + expf(-p.z)));
        q.w = f32_to_bf16_rne(1.0f / (1.0f + expf(-p.w)));
        probs4[i] = q;
    }
    if (i < nc4) ax4[i] = make_float4(0.f, 0.f, 0.f, 0.f);
    if (i < nb) cursor[i] = 0;
    if (i == 0) out[0] = 0.0f;
}

// Phase 1: block counting-sort of 8192 records by bucket (cidx>>13).
// Wave-replicated histogram -> wave-0 shfl scan -> LDS scatter ->
// per-bucket coalesced copy-out.
// Record: {lidx:13 in [31:16] | bf16(val):16}. 4 barriers total.
// hist/lcur layout [wave][bucket] (bank = b%32, ~2-way, free; the
// [bucket][wave] layout was a 16-way conflict: 1.4e7 -> 4.8e6 cycles).
// probs gather is bf16 (2 MB table). NT hints on single-use streams.
__global__ __launch_bounds__(PB) void partition_kernel(
        const int* __restrict__ cidx, const int* __restrict__ vidx,
        const float* __restrict__ coeff, const unsigned short* __restrict__ probs,
        unsigned* __restrict__ cursor, unsigned* __restrict__ recs,
        int nnz4, int nb, unsigned cap) {
    __shared__ unsigned sorted[BLK_RECS];     // 32 KB
    __shared__ unsigned hist[8 * MAXNB];      // [w*64 + b] 2 KB
    __shared__ unsigned lcur[8 * MAXNB];      // running cursors 2 KB
    __shared__ unsigned bst[MAXNB + 1];       // bucket starts in sorted[]
    __shared__ unsigned gbs[MAXNB];           // reserved global bases

    const int tid  = threadIdx.x;
    const int w    = tid >> 6;                // wave 0..7
    const int lane = tid & 63;

    hist[tid] = 0;                            // 512 counters, 512 threads

    // ---- compute this thread's 16 records ----
    unsigned rw[16];
    unsigned bk[16];
    bool     gv[4];
    const unsigned vbase = blockIdx.x * (BLK_RECS / 4);
    const bool full = (vbase + (BLK_RECS / 4)) <= (unsigned)nnz4;

    if (full) {
        #pragma unroll
        for (int g = 0; g < 4; ++g) {
            unsigned v = vbase + g * PB + (unsigned)tid;
            iv4 c4 = __builtin_nontemporal_load((const iv4*)cidx + v);
            iv4 v4 = __builtin_nontemporal_load((const iv4*)vidx + v);
            fv4 w4 = __builtin_nontemporal_load((const fv4*)coeff + v);
            int   cc[4] = {c4.x, c4.y, c4.z, c4.w};
            float vv[4] = {
                w4.x * __builtin_bit_cast(float, (unsigned)probs[v4.x] << 16),
                w4.y * __builtin_bit_cast(float, (unsigned)probs[v4.y] << 16),
                w4.z * __builtin_bit_cast(float, (unsigned)probs[v4.z] << 16),
                w4.w * __builtin_bit_cast(float, (unsigned)probs[v4.w] << 16)};
            #pragma unroll
            for (int j = 0; j < 4; ++j) {
                int k = g * 4 + j;
                unsigned bits = __builtin_bit_cast(unsigned, vv[j]);
                bits += 0x7FFFu + ((bits >> 16) & 1u);     // RNE to bf16
                rw[k] = ((unsigned)(cc[j] & (R_BKT - 1)) << 16) | (bits >> 16);
                bk[k] = (unsigned)cc[j] >> R_LOG2;
            }
            gv[g] = true;
        }
    } else {
        #pragma unroll
        for (int g = 0; g < 4; ++g) {
            unsigned v = vbase + g * PB + (unsigned)tid;
            gv[g] = v < (unsigned)nnz4;
            if (gv[g]) {
                int4   c4 = ((const int4*)cidx)[v];
                int4   v4 = ((const int4*)vidx)[v];
                float4 w4 = ((const float4*)coeff)[v];
                int   cc[4] = {c4.x, c4.y, c4.z, c4.w};
                float vv[4] = {
                    w4.x * __builtin_bit_cast(float, (unsigned)probs[v4.x] << 16),
                    w4.y * __builtin_bit_cast(float, (unsigned)probs[v4.y] << 16),
                    w4.z * __builtin_bit_cast(float, (unsigned)probs[v4.z] << 16),
                    w4.w * __builtin_bit_cast(float, (unsigned)probs[v4.w] << 16)};
                #pragma unroll
                for (int j = 0; j < 4; ++j) {
                    int k = g * 4 + j;
                    unsigned bits = __builtin_bit_cast(unsigned, vv[j]);
                    bits += 0x7FFFu + ((bits >> 16) & 1u);
                    rw[k] = ((unsigned)(cc[j] & (R_BKT - 1)) << 16) | (bits >> 16);
                    bk[k] = (unsigned)cc[j] >> R_LOG2;
                }
            }
        }
    }
    __syncthreads();

    // ---- pass A: wave-replicated histogram ([w][b] layout) ----
    if (full) {
        #pragma unroll
        for (int k = 0; k < 16; ++k)
            atomicAdd(&hist[(w << 6) + bk[k]], 1u);
    } else {
        #pragma unroll
        for (int g = 0; g < 4; ++g) if (gv[g]) {
            #pragma unroll
            for (int j = 0; j < 4; ++j)
                atomicAdd(&hist[(w << 6) + bk[g * 4 + j]], 1u);
        }
    }
    __syncthreads();

    // ---- wave-0: scan bucket totals, set cursors, reserve global space ----
    if (w == 0) {
        unsigned h[8];
        unsigned cnt = 0;
        if (lane < nb) {
            #pragma unroll
            for (int j = 0; j < 8; ++j) { h[j] = hist[(j << 6) + lane]; cnt += h[j]; }
        }
        unsigned sc = cnt;
        #pragma unroll
        for (int d = 1; d < 64; d <<= 1) {
            unsigned t = __shfl_up(sc, d, 64);
            if (lane >= d) sc += t;
        }
        unsigned excl  = sc - cnt;
        unsigned total = __shfl(sc, nb - 1, 64);
        if (lane < nb) {
            bst[lane] = excl;
            unsigned run = excl;
            #pragma unroll
            for (int j = 0; j < 8; ++j) { lcur[(j << 6) + lane] = run; run += h[j]; }
            gbs[lane] = cnt ? atomicAdd(&cursor[lane], cnt) : 0u;
        }
        if (lane == 0) bst[nb] = total;
    }
    __syncthreads();

    // ---- pass B: scatter into sorted LDS ----
    if (full) {
        #pragma unroll
        for (int k = 0; k < 16; ++k) {
            unsigned pos = atomicAdd(&lcur[(w << 6) + bk[k]], 1u);
            sorted[pos] = rw[k];
        }
    } else {
        #pragma unroll
        for (int g = 0; g < 4; ++g) if (gv[g]) {
            #pragma unroll
            for (int j = 0; j < 4; ++j) {
                int k = g * 4 + j;
                unsigned pos = atomicAdd(&lcur[(w << 6) + bk[k]], 1u);
                sorted[pos] = rw[k];
            }
        }
    }
    __syncthreads();

    // ---- copy-out: wave w handles buckets w, w+8, ... (contiguous both sides) ----
    for (int b = w; b < nb; b += 8) {
        unsigned st = bst[b], en = bst[b + 1], gb = gbs[b];
        unsigned* dst = recs + (size_t)b * cap;
        for (unsigned p = st + (unsigned)lane; p < en; p += 64u) {
            unsigned pos = gb + (p - st);
            if (pos < cap) __builtin_nontemporal_store(sorted[p], &dst[pos]);
        }
    }
}

// Phase 2: block (b,s) accumulates slice s of bucket b into LDS via ds_add,
// vec4 NT record loads, then adds the tile into ax with coalesced global
// f32 atomics (replaces the 32 MB partial-write + 32 MB reduce-read).
__global__ __launch_bounds__(256) void accum_kernel(
        const unsigned* __restrict__ recs, const unsigned* __restrict__ cursor,
        float* __restrict__ ax, int n_constrs, unsigned cap) {
    __shared__ float acc[R_BKT];
    const int b = blockIdx.x / SLICE;
    const int s = blockIdx.x % SLICE;
    for (int j = threadIdx.x * 4; j < R_BKT; j += blockDim.x * 4)
        *(float4*)(acc + j) = make_float4(0.f, 0.f, 0.f, 0.f);
    __syncthreads();

    unsigned cnt = cursor[b];
    if (cnt > cap) cnt = cap;
    const unsigned* base = recs + (size_t)b * cap;

    unsigned c4 = cnt >> 2;
    unsigned s4 = (unsigned)(((unsigned long long)c4 * s) / SLICE);
    unsigned e4 = (unsigned)(((unsigned long long)c4 * (s + 1)) / SLICE);
    const uv4* b4 = (const uv4*)base;
    #pragma unroll 2
    for (unsigned i = s4 + threadIdx.x; i < e4; i += blockDim.x) {
        uv4 r = __builtin_nontemporal_load(b4 + i);
        unsafeAtomicAdd(&acc[r.x >> 16], __builtin_bit_cast(float, (r.x & 0xFFFFu) << 16));
        unsafeAtomicAdd(&acc[r.y >> 16], __builtin_bit_cast(float, (r.y & 0xFFFFu) << 16));
        unsafeAtomicAdd(&acc[r.z >> 16], __builtin_bit_cast(float, (r.z & 0xFFFFu) << 16));
        unsafeAtomicAdd(&acc[r.w >> 16], __builtin_bit_cast(float, (r.w & 0xFFFFu) << 16));
    }
    if (s == SLICE - 1) {
        for (unsigned i = (c4 << 2) + threadIdx.x; i < cnt; i += blockDim.x) {
            unsigned r = base[i];
            unsafeAtomicAdd(&acc[r >> 16], __builtin_bit_cast(float, (r & 0xFFFFu) << 16));
        }
    }
    __syncthreads();

    const int gb = b * R_BKT;
    for (int j = threadIdx.x; j < R_BKT; j += blockDim.x) {
        int g = gb + j;
        if (g < n_constrs)
            unsafeAtomicAdd(&ax[g], acc[j]);   // coalesced consecutive dwords
    }
}

// Phase 3: violation by sense from ax, mean. (6 MB total traffic.)
__device__ __forceinline__ float viol(float d, int sn) {
    return (sn == 1) ? fmaxf(d, 0.0f)
         : (sn == 2) ? fmaxf(-d, 0.0f)
         : (sn == 3) ? fabsf(d)
         : 0.0f;
}

__global__ void reduce_fast(const float4* __restrict__ ax4,
                            const float4* __restrict__ rhs4,
                            const int4* __restrict__ sense4,
                            float* __restrict__ out,
                            int n4, float inv_n) {
    int i = blockIdx.x * blockDim.x + threadIdx.x;
    float v = 0.0f;
    if (i < n4) {
        float4 a = ax4[i];
        float4 r = rhs4[i];
        int4  sn = sense4[i];
        v = viol(a.x - r.x, sn.x) + viol(a.y - r.y, sn.y)
          + viol(a.z - r.z, sn.z) + viol(a.w - r.w, sn.w);
    }
    #pragma unroll
    for (int off = 32; off > 0; off >>= 1)
        v += __shfl_down(v, off, 64);
    __shared__ float wsum[4];
    int lane = threadIdx.x & 63;
    int wid  = threadIdx.x >> 6;
    if (lane == 0) wsum[wid] = v;
    __syncthreads();
    if (threadIdx.x == 0)
        atomicAdd(out, (wsum[0] + wsum[1] + wsum[2] + wsum[3]) * inv_n);
}

// ======================= fallback path (small ws) =======================

__global__ void init_kernel(const float* __restrict__ pred,
                            float* __restrict__ probs,
                            float* __restrict__ ax,
                            float* __restrict__ out,
                            int n_vars, int n_constrs) {
    int i = blockIdx.x * blockDim.x + threadIdx.x;
    if (i < n_vars) probs[i] = 1.0f / (1.0f + expf(-pred[i]));
    if (i < n_constrs) ax[i] = 0.0f;
    if (i == 0) out[0] = 0.0f;
}

__global__ void scatter_kernel(const int* __restrict__ cidx,
                               const int* __restrict__ vidx,
                               const float* __restrict__ coeff,
                               const float* __restrict__ probs,
                               float* __restrict__ ax,
                               int nnz) {
    int i = blockIdx.x * blockDim.x + threadIdx.x;
    long long base = (long long)i * 4;
    if (base + 3 < (long long)nnz) {
        int4   c = ((const int4*)cidx)[i];
        int4   v = ((const int4*)vidx)[i];
        float4 w = ((const float4*)coeff)[i];
        unsafeAtomicAdd(&ax[c.x], w.x * probs[v.x]);
        unsafeAtomicAdd(&ax[c.y], w.y * probs[v.y]);
        unsafeAtomicAdd(&ax[c.z], w.z * probs[v.z]);
        unsafeAtomicAdd(&ax[c.w], w.w * probs[v.w]);
    } else if (base < (long long)nnz) {
        for (long long k = base; k < (long long)nnz; ++k)
            unsafeAtomicAdd(&ax[cidx[k]], coeff[k] * probs[vidx[k]]);
    }
}

__global__ void reduce_kernel(const float* __restrict__ ax,
                              const float* __restrict__ rhs,
                              const int* __restrict__ sense,
                              float* __restrict__ out,
                              int n_constrs, float inv_n) {
    int i = blockIdx.x * blockDim.x + threadIdx.x;
    float v = 0.0f;
    if (i < n_constrs) {
        float d = ax[i] - rhs[i];
        int s = sense[i];
        v = (s == 1) ? fmaxf(d, 0.0f)
          : (s == 2) ? fmaxf(-d, 0.0f)
          : (s == 3) ? fabsf(d)
          : 0.0f;
    }
    #pragma unroll
    for (int off = 32; off > 0; off >>= 1)
        v += __shfl_down(v, off, 64);
    __shared__ float wsum[4];
    int lane = threadIdx.x & 63;
    int wid  = threadIdx.x >> 6;
    if (lane == 0) wsum[wid] = v;
    __syncthreads();
    if (threadIdx.x == 0)
        atomicAdd(out, (wsum[0] + wsum[1] + wsum[2] + wsum[3]) * inv_n);
}

// ============================== launch ==============================

static inline size_t align16(size_t x) { return (x + 15) & ~(size_t)15; }

extern "C" void kernel_launch(void* const* d_in, const int* in_sizes, int n_in,
                              void* d_out, int out_size, void* d_ws, size_t ws_size,
                              hipStream_t stream) {
    const float* pred  = (const float*)d_in[0];
    const int*   cidx  = (const int*)d_in[1];
    const int*   vidx  = (const int*)d_in[2];
    const float* coeff = (const float*)d_in[3];
    const float* rhs   = (const float*)d_in[4];
    const int*   sense = (const int*)d_in[5];

    const int n_vars    = in_sizes[0];
    const int nnz       = in_sizes[1];
    const int n_constrs = in_sizes[4];
    const int B = 256;
    const float inv_n = 1.0f / (float)n_constrs;

    const int nb = (n_constrs + R_BKT - 1) / R_BKT;
    unsigned cap = (unsigned)(((double)nnz * R_BKT / (double)n_constrs) * 1.0625) + 1024;
    cap = (cap + 3u) & ~3u;   // 16B alignment for uint4 loads in accum

    // fast-path workspace layout
    size_t off_probs  = 0;                                      // bf16, n_vars*2
    size_t off_cursor = align16(off_probs + (size_t)n_vars * 2);
    size_t off_recs   = align16(off_cursor + (size_t)nb * 4);
    size_t off_ax     = align16(off_recs + (size_t)nb * cap * 4);
    size_t need_fast  = off_ax + (size_t)n_constrs * 4;

    bool fast = (ws_size >= need_fast) && (nb <= MAXNB) && ((nnz & 3) == 0)
             && ((n_vars & 3) == 0) && ((n_constrs & 3) == 0);

    if (fast) {
        unsigned short* probs  = (unsigned short*)((char*)d_ws + off_probs);
        unsigned*       cursor = (unsigned*)((char*)d_ws + off_cursor);
        unsigned*       recs   = (unsigned*)((char*)d_ws + off_recs);
        float*          ax     = (float*)((char*)d_ws + off_ax);
        float*          out    = (float*)d_out;

        int n_vars4 = n_vars >> 2;
        int nc4     = n_constrs >> 2;
        int init_n  = n_vars4 > nc4 ? n_vars4 : nc4;
        if (init_n < nb) init_n = nb;
        init_fast<<<(init_n + B - 1) / B, B, 0, stream>>>(
            (const float4*)pred, (ushort4*)probs, (float4*)ax, cursor, out,
            n_vars4, nc4, nb);

        int nnz4 = nnz >> 2;
        int nblk1 = (nnz4 + (BLK_RECS / 4) - 1) / (BLK_RECS / 4);
        partition_kernel<<<nblk1, PB, 0, stream>>>(
            cidx, vidx, coeff, probs, cursor, recs, nnz4, nb, cap);

        accum_kernel<<<nb * SLICE, B, 0, stream>>>(
            recs, cursor, ax, n_constrs, cap);

        reduce_fast<<<(nc4 + B - 1) / B, B, 0, stream>>>(
            (const float4*)ax, (const float4*)rhs, (const int4*)sense,
            out, nc4, inv_n);
    } else {
        float* probs = (float*)d_ws;
        float* ax    = probs + n_vars;
        float* out   = (float*)d_out;

        int init_n = n_vars > n_constrs ? n_vars : n_constrs;
        init_kernel<<<(init_n + B - 1) / B, B, 0, stream>>>(
            pred, probs, ax, out, n_vars, n_constrs);

        int n_vec_threads = (nnz + 3) / 4;
        scatter_kernel<<<(n_vec_threads + B - 1) / B, B, 0, stream>>>(
            cidx, vidx, coeff, probs, ax, nnz);

        reduce_kernel<<<(n_constrs + B - 1) / B, B, 0, stream>>>(
            ax, rhs, sense, out, n_constrs, inv_n);
    }
}

// Round 8
// 439.202 us; speedup vs baseline: 1.0491x; 1.0187x over previous
//
#include <hip/hip_runtime.h>
#include <math.h>

#define R_LOG2 13
#define R_BKT  8192      // constraints per bucket (32 KB LDS accumulator)
#define NSTRIPE 8        // cursor/recs stripes = accum blocks per bucket
#define MAXNB  64        // max buckets supported by fast path
#define PB     512       // partition block size (8 waves)
#define BLK_RECS 8192    // records per partition block

// clang ext-vector types: required by __builtin_nontemporal_load/store
// (HIP_vector_type wrappers are rejected by the builtin).
typedef int      iv4 __attribute__((ext_vector_type(4)));
typedef float    fv4 __attribute__((ext_vector_type(4)));
typedef unsigned uv4 __attribute__((ext_vector_type(4)));

__device__ __forceinline__ unsigned short f32_to_bf16_rne(float f) {
    unsigned b = __builtin_bit_cast(unsigned, f);
    b += 0x7FFFu + ((b >> 16) & 1u);
    return (unsigned short)(b >> 16);
}

// ============================= fast path =============================

// probs = bf16(sigmoid(pred)) — 2 MB table stays L2-resident (measured:
// FETCH 179->125 MB). Zeroes striped cursors (8*64), ax, out.
__global__ void init_fast(const float4* __restrict__ pred4,
                          ushort4* __restrict__ probs4,
                          float4* __restrict__ ax4,
                          unsigned* __restrict__ cursor,
                          float* __restrict__ out,
                          int n_vars4, int nc4) {
    int i = blockIdx.x * blockDim.x + threadIdx.x;
    if (i < n_vars4) {
        float4 p = pred4[i];
        ushort4 q;
        q.x = f32_to_bf16_rne(1.0f / (1.0f + expf(-p.x)));
        q.y = f32_to_bf16_rne(1.0f / (1.0f + expf(-p.y)));
        q.z = f32_to_bf16_rne(1.0f / (1.0f + expf(-p.z)));
        q.w = f32_to_bf16_rne(1.0f / (1.0f + expf(-p.w)));
        probs4[i] = q;
    }
    if (i < nc4) ax4[i] = make_float4(0.f, 0.f, 0.f, 0.f);
    if (i < MAXNB * NSTRIPE) cursor[i] = 0;
    if (i == 0) out[0] = 0.0f;
}

// Phase 1: block counting-sort of 8192 records by bucket (cidx>>13).
// Phase order: cidx load -> hist (LDS) -> value loads/gathers issued so
// their latency overlaps hist+scan -> wave0 scan || wave1 global cursor
// atomic (8-way striped: replica blockIdx&7 -> 8x less line contention,
// and off wave0's critical path) -> scatter -> striped copy-out.
// Record: {lidx:13 in [31:16] | bf16(val):16}.
__global__ __launch_bounds__(PB) void partition_kernel(
        const int* __restrict__ cidx, const int* __restrict__ vidx,
        const float* __restrict__ coeff, const unsigned short* __restrict__ probs,
        unsigned* __restrict__ cursor, unsigned* __restrict__ recs,
        int nnz4, int nb, unsigned scap) {
    __shared__ unsigned sorted[BLK_RECS];     // 32 KB
    __shared__ unsigned hist[8 * MAXNB];      // [w*64 + b] 2 KB
    __shared__ unsigned lcur[8 * MAXNB];      // running cursors 2 KB
    __shared__ unsigned bst[MAXNB + 1];       // bucket starts in sorted[]
    __shared__ unsigned gbs[MAXNB];           // reserved global bases

    const int tid  = threadIdx.x;
    const int w    = tid >> 6;                // wave 0..7
    const int lane = tid & 63;
    const int rep  = blockIdx.x & (NSTRIPE - 1);

    hist[tid] = 0;                            // 512 counters, 512 threads

    unsigned rw[16];                          // (lidx<<16), later |= bf16
    unsigned bkp[4];                          // 4 buckets packed per word
    bool     gv[4];
    const unsigned vbase = blockIdx.x * (BLK_RECS / 4);
    const bool full = (vbase + (BLK_RECS / 4)) <= (unsigned)nnz4;

    // ---- phase 0: cidx load, bucket/lidx extraction ----
    if (full) {
        #pragma unroll
        for (int g = 0; g < 4; ++g) {
            unsigned v = vbase + g * PB + (unsigned)tid;
            iv4 c4 = __builtin_nontemporal_load((const iv4*)cidx + v);
            int cc[4] = {c4.x, c4.y, c4.z, c4.w};
            bkp[g] = ((unsigned)cc[0] >> R_LOG2)
                   | (((unsigned)cc[1] >> R_LOG2) << 8)
                   | (((unsigned)cc[2] >> R_LOG2) << 16)
                   | (((unsigned)cc[3] >> R_LOG2) << 24);
            #pragma unroll
            for (int j = 0; j < 4; ++j)
                rw[g * 4 + j] = (unsigned)(cc[j] & (R_BKT - 1)) << 16;
            gv[g] = true;
        }
    } else {
        #pragma unroll
        for (int g = 0; g < 4; ++g) {
            unsigned v = vbase + g * PB + (unsigned)tid;
            gv[g] = v < (unsigned)nnz4;
            bkp[g] = 0;
            if (gv[g]) {
                int4 c4 = ((const int4*)cidx)[v];
                int cc[4] = {c4.x, c4.y, c4.z, c4.w};
                bkp[g] = ((unsigned)cc[0] >> R_LOG2)
                       | (((unsigned)cc[1] >> R_LOG2) << 8)
                       | (((unsigned)cc[2] >> R_LOG2) << 16)
                       | (((unsigned)cc[3] >> R_LOG2) << 24);
                #pragma unroll
                for (int j = 0; j < 4; ++j)
                    rw[g * 4 + j] = (unsigned)(cc[j] & (R_BKT - 1)) << 16;
            }
        }
    }
    __syncthreads();   // hist zeros visible

    // ---- phase A: wave-replicated histogram ([w][b] layout) ----
    if (full) {
        #pragma unroll
        for (int g = 0; g < 4; ++g)
            #pragma unroll
            for (int j = 0; j < 4; ++j)
                atomicAdd(&hist[(w << 6) + ((bkp[g] >> (8 * j)) & 0xFFu)], 1u);
    } else {
        #pragma unroll
        for (int g = 0; g < 4; ++g) if (gv[g]) {
            #pragma unroll
            for (int j = 0; j < 4; ++j)
                atomicAdd(&hist[(w << 6) + ((bkp[g] >> (8 * j)) & 0xFFu)], 1u);
        }
    }

    // ---- phase A2: value loads + gathers (latency overlaps hist/scan) ----
    if (full) {
        #pragma unroll
        for (int g = 0; g < 4; ++g) {
            unsigned v = vbase + g * PB + (unsigned)tid;
            iv4 v4 = __builtin_nontemporal_load((const iv4*)vidx + v);
            fv4 w4 = __builtin_nontemporal_load((const fv4*)coeff + v);
            int   vi[4] = {v4.x, v4.y, v4.z, v4.w};
            float wc[4] = {w4.x, w4.y, w4.z, w4.w};
            #pragma unroll
            for (int j = 0; j < 4; ++j) {
                float pv = __builtin_bit_cast(float, (unsigned)probs[vi[j]] << 16);
                unsigned bits = __builtin_bit_cast(unsigned, wc[j] * pv);
                bits += 0x7FFFu + ((bits >> 16) & 1u);     // RNE to bf16
                rw[g * 4 + j] |= bits >> 16;
            }
        }
    } else {
        #pragma unroll
        for (int g = 0; g < 4; ++g) if (gv[g]) {
            unsigned v = vbase + g * PB + (unsigned)tid;
            int4   v4 = ((const int4*)vidx)[v];
            float4 w4 = ((const float4*)coeff)[v];
            int   vi[4] = {v4.x, v4.y, v4.z, v4.w};
            float wc[4] = {w4.x, w4.y, w4.z, w4.w};
            #pragma unroll
            for (int j = 0; j < 4; ++j) {
                float pv = __builtin_bit_cast(float, (unsigned)probs[vi[j]] << 16);
                unsigned bits = __builtin_bit_cast(unsigned, wc[j] * pv);
                bits += 0x7FFFu + ((bits >> 16) & 1u);
                rw[g * 4 + j] |= bits >> 16;
            }
        }
    }
    __syncthreads();   // hist complete

    // ---- wave0: scan + local cursors; wave1: global reservation (parallel) ----
    if (w == 0) {
        unsigned h[8];
        unsigned cnt = 0;
        if (lane < nb) {
            #pragma unroll
            for (int j = 0; j < 8; ++j) { h[j] = hist[(j << 6) + lane]; cnt += h[j]; }
        }
        unsigned sc = cnt;
        #pragma unroll
        for (int d = 1; d < 64; d <<= 1) {
            unsigned t = __shfl_up(sc, d, 64);
            if (lane >= d) sc += t;
        }
        unsigned excl  = sc - cnt;
        unsigned total = __shfl(sc, nb - 1, 64);
        if (lane < nb) {
            bst[lane] = excl;
            unsigned run = excl;
            #pragma unroll
            for (int j = 0; j < 8; ++j) { lcur[(j << 6) + lane] = run; run += h[j]; }
        }
        if (lane == 0) bst[nb] = total;
    } else if (w == 1) {
        if (lane < nb) {
            unsigned cnt2 = 0;
            #pragma unroll
            for (int j = 0; j < 8; ++j) cnt2 += hist[(j << 6) + lane];
            gbs[lane] = cnt2 ? atomicAdd(&cursor[rep * MAXNB + lane], cnt2) : 0u;
        }
    }
    __syncthreads();   // lcur/bst ready (gbs too)

    // ---- pass B: scatter into sorted LDS ----
    if (full) {
        #pragma unroll
        for (int g = 0; g < 4; ++g)
            #pragma unroll
            for (int j = 0; j < 4; ++j) {
                unsigned b = (bkp[g] >> (8 * j)) & 0xFFu;
                unsigned pos = atomicAdd(&lcur[(w << 6) + b], 1u);
                sorted[pos] = rw[g * 4 + j];
            }
    } else {
        #pragma unroll
        for (int g = 0; g < 4; ++g) if (gv[g]) {
            #pragma unroll
            for (int j = 0; j < 4; ++j) {
                unsigned b = (bkp[g] >> (8 * j)) & 0xFFu;
                unsigned pos = atomicAdd(&lcur[(w << 6) + b], 1u);
                sorted[pos] = rw[g * 4 + j];
            }
        }
    }
    __syncthreads();   // sorted + gbs ready

    // ---- copy-out: wave w handles buckets w, w+8, ... into stripe rep ----
    for (int b = w; b < nb; b += 8) {
        unsigned st = bst[b], en = bst[b + 1], gb = gbs[b];
        unsigned* dst = recs + (size_t)(b * NSTRIPE + rep) * scap;
        for (unsigned p = st + (unsigned)lane; p < en; p += 64u) {
            unsigned pos = gb + (p - st);
            if (pos < scap) __builtin_nontemporal_store(sorted[p], &dst[pos]);
        }
    }
}

// Phase 2: block (b,s) accumulates stripe s of bucket b into LDS via ds_add,
// vec4 NT record loads, then adds the tile into ax with coalesced global
// f32 atomics.
__global__ __launch_bounds__(256) void accum_kernel(
        const unsigned* __restrict__ recs, const unsigned* __restrict__ cursor,
        float* __restrict__ ax, int n_constrs, unsigned scap) {
    __shared__ float acc[R_BKT];
    const int b = blockIdx.x >> 3;            // bucket
    const int s = blockIdx.x & (NSTRIPE - 1); // stripe
    for (int j = threadIdx.x * 4; j < R_BKT; j += blockDim.x * 4)
        *(float4*)(acc + j) = make_float4(0.f, 0.f, 0.f, 0.f);
    __syncthreads();

    unsigned cnt = cursor[s * MAXNB + b];
    if (cnt > scap) cnt = scap;
    const unsigned* base = recs + (size_t)(b * NSTRIPE + s) * scap;

    unsigned c4 = cnt >> 2;
    const uv4* b4 = (const uv4*)base;
    #pragma unroll 2
    for (unsigned i = threadIdx.x; i < c4; i += blockDim.x) {
        uv4 r = __builtin_nontemporal_load(b4 + i);
        unsafeAtomicAdd(&acc[r.x >> 16], __builtin_bit_cast(float, (r.x & 0xFFFFu) << 16));
        unsafeAtomicAdd(&acc[r.y >> 16], __builtin_bit_cast(float, (r.y & 0xFFFFu) << 16));
        unsafeAtomicAdd(&acc[r.z >> 16], __builtin_bit_cast(float, (r.z & 0xFFFFu) << 16));
        unsafeAtomicAdd(&acc[r.w >> 16], __builtin_bit_cast(float, (r.w & 0xFFFFu) << 16));
    }
    for (unsigned i = (c4 << 2) + threadIdx.x; i < cnt; i += blockDim.x) {
        unsigned r = base[i];
        unsafeAtomicAdd(&acc[r >> 16], __builtin_bit_cast(float, (r & 0xFFFFu) << 16));
    }
    __syncthreads();

    const int gb = b * R_BKT;
    for (int j = threadIdx.x; j < R_BKT; j += blockDim.x) {
        int g = gb + j;
        if (g < n_constrs)
            unsafeAtomicAdd(&ax[g], acc[j]);   // coalesced consecutive dwords
    }
}

// Phase 3: violation by sense from ax, mean. (6 MB total traffic.)
__device__ __forceinline__ float viol(float d, int sn) {
    return (sn == 1) ? fmaxf(d, 0.0f)
         : (sn == 2) ? fmaxf(-d, 0.0f)
         : (sn == 3) ? fabsf(d)
         : 0.0f;
}

__global__ void reduce_fast(const float4* __restrict__ ax4,
                            const float4* __restrict__ rhs4,
                            const int4* __restrict__ sense4,
                            float* __restrict__ out,
                            int n4, float inv_n) {
    int i = blockIdx.x * blockDim.x + threadIdx.x;
    float v = 0.0f;
    if (i < n4) {
        float4 a = ax4[i];
        float4 r = rhs4[i];
        int4  sn = sense4[i];
        v = viol(a.x - r.x, sn.x) + viol(a.y - r.y, sn.y)
          + viol(a.z - r.z, sn.z) + viol(a.w - r.w, sn.w);
    }
    #pragma unroll
    for (int off = 32; off > 0; off >>= 1)
        v += __shfl_down(v, off, 64);
    __shared__ float wsum[4];
    int lane = threadIdx.x & 63;
    int wid  = threadIdx.x >> 6;
    if (lane == 0) wsum[wid] = v;
    __syncthreads();
    if (threadIdx.x == 0)
        atomicAdd(out, (wsum[0] + wsum[1] + wsum[2] + wsum[3]) * inv_n);
}

// ======================= fallback path (small ws) =======================

__global__ void init_kernel(const float* __restrict__ pred,
                            float* __restrict__ probs,
                            float* __restrict__ ax,
                            float* __restrict__ out,
                            int n_vars, int n_constrs) {
    int i = blockIdx.x * blockDim.x + threadIdx.x;
    if (i < n_vars) probs[i] = 1.0f / (1.0f + expf(-pred[i]));
    if (i < n_constrs) ax[i] = 0.0f;
    if (i == 0) out[0] = 0.0f;
}

__global__ void scatter_kernel(const int* __restrict__ cidx,
                               const int* __restrict__ vidx,
                               const float* __restrict__ coeff,
                               const float* __restrict__ probs,
                               float* __restrict__ ax,
                               int nnz) {
    int i = blockIdx.x * blockDim.x + threadIdx.x;
    long long base = (long long)i * 4;
    if (base + 3 < (long long)nnz) {
        int4   c = ((const int4*)cidx)[i];
        int4   v = ((const int4*)vidx)[i];
        float4 w = ((const float4*)coeff)[i];
        unsafeAtomicAdd(&ax[c.x], w.x * probs[v.x]);
        unsafeAtomicAdd(&ax[c.y], w.y * probs[v.y]);
        unsafeAtomicAdd(&ax[c.z], w.z * probs[v.z]);
        unsafeAtomicAdd(&ax[c.w], w.w * probs[v.w]);
    } else if (base < (long long)nnz) {
        for (long long k = base; k < (long long)nnz; ++k)
            unsafeAtomicAdd(&ax[cidx[k]], coeff[k] * probs[vidx[k]]);
    }
}

__global__ void reduce_kernel(const float* __restrict__ ax,
                              const float* __restrict__ rhs,
                              const int* __restrict__ sense,
                              float* __restrict__ out,
                              int n_constrs, float inv_n) {
    int i = blockIdx.x * blockDim.x + threadIdx.x;
    float v = 0.0f;
    if (i < n_constrs) {
        float d = ax[i] - rhs[i];
        int s = sense[i];
        v = (s == 1) ? fmaxf(d, 0.0f)
          : (s == 2) ? fmaxf(-d, 0.0f)
          : (s == 3) ? fabsf(d)
          : 0.0f;
    }
    #pragma unroll
    for (int off = 32; off > 0; off >>= 1)
        v += __shfl_down(v, off, 64);
    __shared__ float wsum[4];
    int lane = threadIdx.x & 63;
    int wid  = threadIdx.x >> 6;
    if (lane == 0) wsum[wid] = v;
    __syncthreads();
    if (threadIdx.x == 0)
        atomicAdd(out, (wsum[0] + wsum[1] + wsum[2] + wsum[3]) * inv_n);
}

// ============================== launch ==============================

static inline size_t align16(size_t x) { return (x + 15) & ~(size_t)15; }

extern "C" void kernel_launch(void* const* d_in, const int* in_sizes, int n_in,
                              void* d_out, int out_size, void* d_ws, size_t ws_size,
                              hipStream_t stream) {
    const float* pred  = (const float*)d_in[0];
    const int*   cidx  = (const int*)d_in[1];
    const int*   vidx  = (const int*)d_in[2];
    const float* coeff = (const float*)d_in[3];
    const float* rhs   = (const float*)d_in[4];
    const int*   sense = (const int*)d_in[5];

    const int n_vars    = in_sizes[0];
    const int nnz       = in_sizes[1];
    const int n_constrs = in_sizes[4];
    const int B = 256;
    const float inv_n = 1.0f / (float)n_constrs;

    const int nb = (n_constrs + R_BKT - 1) / R_BKT;
    unsigned scap = (unsigned)(((double)nnz * R_BKT / (double)n_constrs / NSTRIPE)
                               * 1.0625) + 1024;
    scap = (scap + 3u) & ~3u;   // 16B alignment for uint4 loads in accum

    // fast-path workspace layout
    size_t off_probs  = 0;                                      // bf16, n_vars*2
    size_t off_cursor = align16(off_probs + (size_t)n_vars * 2);
    size_t off_recs   = align16(off_cursor + (size_t)MAXNB * NSTRIPE * 4);
    size_t off_ax     = align16(off_recs + (size_t)nb * NSTRIPE * scap * 4);
    size_t need_fast  = off_ax + (size_t)n_constrs * 4;

    bool fast = (ws_size >= need_fast) && (nb <= MAXNB) && ((nnz & 3) == 0)
             && ((n_vars & 3) == 0) && ((n_constrs & 3) == 0);

    if (fast) {
        unsigned short* probs  = (unsigned short*)((char*)d_ws + off_probs);
        unsigned*       cursor = (unsigned*)((char*)d_ws + off_cursor);
        unsigned*       recs   = (unsigned*)((char*)d_ws + off_recs);
        float*          ax     = (float*)((char*)d_ws + off_ax);
        float*          out    = (float*)d_out;

        int n_vars4 = n_vars >> 2;
        int nc4     = n_constrs >> 2;
        int init_n  = n_vars4 > nc4 ? n_vars4 : nc4;
        if (init_n < MAXNB * NSTRIPE) init_n = MAXNB * NSTRIPE;
        init_fast<<<(init_n + B - 1) / B, B, 0, stream>>>(
            (const float4*)pred, (ushort4*)probs, (float4*)ax, cursor, out,
            n_vars4, nc4);

        int nnz4 = nnz >> 2;
        int nblk1 = (nnz4 + (BLK_RECS / 4) - 1) / (BLK_RECS / 4);
        partition_kernel<<<nblk1, PB, 0, stream>>>(
            cidx, vidx, coeff, probs, cursor, recs, nnz4, nb, scap);

        accum_kernel<<<nb * NSTRIPE, B, 0, stream>>>(
            recs, cursor, ax, n_constrs, scap);

        reduce_fast<<<(nc4 + B - 1) / B, B, 0, stream>>>(
            (const float4*)ax, (const float4*)rhs, (const int4*)sense,
            out, nc4, inv_n);
    } else {
        float* probs = (float*)d_ws;
        float* ax    = probs + n_vars;
        float* out   = (float*)d_out;

        int init_n = n_vars > n_constrs ? n_vars : n_constrs;
        init_kernel<<<(init_n + B - 1) / B, B, 0, stream>>>(
            pred, probs, ax, out, n_vars, n_constrs);

        int n_vec_threads = (nnz + 3) / 4;
        scatter_kernel<<<(n_vec_threads + B - 1) / B, B, 0, stream>>>(
            cidx, vidx, coeff, probs, ax, nnz);

        reduce_kernel<<<(n_constrs + B - 1) / B, B, 0, stream>>>(
            ax, rhs, sense, out, n_constrs, inv_n);
    }
}

// Round 9
// 438.846 us; speedup vs baseline: 1.0500x; 1.0008x over previous
//
#include <hip/hip_runtime.h>
#include <math.h>

#define R_LOG2 13
#define R_BKT  8192      // constraints per bucket (32 KB LDS accumulator)
#define NSTRIPE 16       // cursor/recs stripes = accum blocks per bucket
#define MAXNB  64        // max buckets supported by fast path
#define PB     512       // partition block size (8 waves)
#define BLK_RECS 8192    // records per partition block

// clang ext-vector types: required by __builtin_nontemporal_load/store
// (HIP_vector_type wrappers are rejected by the builtin).
typedef int      iv4 __attribute__((ext_vector_type(4)));
typedef float    fv4 __attribute__((ext_vector_type(4)));
typedef unsigned uv4 __attribute__((ext_vector_type(4)));

__device__ __forceinline__ unsigned short f32_to_bf16_rne(float f) {
    unsigned b = __builtin_bit_cast(unsigned, f);
    b += 0x7FFFu + ((b >> 16) & 1u);
    return (unsigned short)(b >> 16);
}

// ============================= fast path =============================

// probs = bf16(sigmoid(pred)) — 2 MB table stays L2-resident (measured:
// FETCH 179->125 MB). Zeroes striped cursors (16*64), ax, out.
__global__ void init_fast(const float4* __restrict__ pred4,
                          ushort4* __restrict__ probs4,
                          float4* __restrict__ ax4,
                          unsigned* __restrict__ cursor,
                          float* __restrict__ out,
                          int n_vars4, int nc4) {
    int i = blockIdx.x * blockDim.x + threadIdx.x;
    if (i < n_vars4) {
        float4 p = pred4[i];
        ushort4 q;
        q.x = f32_to_bf16_rne(1.0f / (1.0f + expf(-p.x)));
        q.y = f32_to_bf16_rne(1.0f / (1.0f + expf(-p.y)));
        q.z = f32_to_bf16_rne(1.0f / (1.0f + expf(-p.z)));
        q.w = f32_to_bf16_rne(1.0f / (1.0f + expf(-p.w)));
        probs4[i] = q;
    }
    if (i < nc4) ax4[i] = make_float4(0.f, 0.f, 0.f, 0.f);
    if (i < MAXNB * NSTRIPE) cursor[i] = 0;
    if (i == 0) out[0] = 0.0f;
}

// Phase 1: block counting-sort of 8192 records by bucket (cidx>>13).
// cidx load -> hist (LDS) -> value loads/gathers (latency overlaps
// hist+scan) -> wave0 scan || wave1 global cursor atomic (16-way striped)
// -> scatter -> striped copy-out. recs store is CACHED (not NT) so accum
// can hit the tail of it in L2. Record: {lidx:13 | bf16:16}.
__global__ __launch_bounds__(PB) void partition_kernel(
        const int* __restrict__ cidx, const int* __restrict__ vidx,
        const float* __restrict__ coeff, const unsigned short* __restrict__ probs,
        unsigned* __restrict__ cursor, unsigned* __restrict__ recs,
        int nnz4, int nb, unsigned scap) {
    __shared__ unsigned sorted[BLK_RECS];     // 32 KB
    __shared__ unsigned hist[8 * MAXNB];      // [w*64 + b] 2 KB
    __shared__ unsigned lcur[8 * MAXNB];      // running cursors 2 KB
    __shared__ unsigned bst[MAXNB + 1];       // bucket starts in sorted[]
    __shared__ unsigned gbs[MAXNB];           // reserved global bases

    const int tid  = threadIdx.x;
    const int w    = tid >> 6;                // wave 0..7
    const int lane = tid & 63;
    const int rep  = blockIdx.x & (NSTRIPE - 1);

    hist[tid] = 0;                            // 512 counters, 512 threads

    unsigned rw[16];                          // (lidx<<16), later |= bf16
    unsigned bkp[4];                          // 4 buckets packed per word
    bool     gv[4];
    const unsigned vbase = blockIdx.x * (BLK_RECS / 4);
    const bool full = (vbase + (BLK_RECS / 4)) <= (unsigned)nnz4;

    // ---- phase 0: cidx load, bucket/lidx extraction ----
    if (full) {
        #pragma unroll
        for (int g = 0; g < 4; ++g) {
            unsigned v = vbase + g * PB + (unsigned)tid;
            iv4 c4 = __builtin_nontemporal_load((const iv4*)cidx + v);
            int cc[4] = {c4.x, c4.y, c4.z, c4.w};
            bkp[g] = ((unsigned)cc[0] >> R_LOG2)
                   | (((unsigned)cc[1] >> R_LOG2) << 8)
                   | (((unsigned)cc[2] >> R_LOG2) << 16)
                   | (((unsigned)cc[3] >> R_LOG2) << 24);
            #pragma unroll
            for (int j = 0; j < 4; ++j)
                rw[g * 4 + j] = (unsigned)(cc[j] & (R_BKT - 1)) << 16;
            gv[g] = true;
        }
    } else {
        #pragma unroll
        for (int g = 0; g < 4; ++g) {
            unsigned v = vbase + g * PB + (unsigned)tid;
            gv[g] = v < (unsigned)nnz4;
            bkp[g] = 0;
            if (gv[g]) {
                int4 c4 = ((const int4*)cidx)[v];
                int cc[4] = {c4.x, c4.y, c4.z, c4.w};
                bkp[g] = ((unsigned)cc[0] >> R_LOG2)
                       | (((unsigned)cc[1] >> R_LOG2) << 8)
                       | (((unsigned)cc[2] >> R_LOG2) << 16)
                       | (((unsigned)cc[3] >> R_LOG2) << 24);
                #pragma unroll
                for (int j = 0; j < 4; ++j)
                    rw[g * 4 + j] = (unsigned)(cc[j] & (R_BKT - 1)) << 16;
            }
        }
    }
    __syncthreads();   // hist zeros visible

    // ---- phase A: wave-replicated histogram ([w][b] layout) ----
    if (full) {
        #pragma unroll
        for (int g = 0; g < 4; ++g)
            #pragma unroll
            for (int j = 0; j < 4; ++j)
                atomicAdd(&hist[(w << 6) + ((bkp[g] >> (8 * j)) & 0xFFu)], 1u);
    } else {
        #pragma unroll
        for (int g = 0; g < 4; ++g) if (gv[g]) {
            #pragma unroll
            for (int j = 0; j < 4; ++j)
                atomicAdd(&hist[(w << 6) + ((bkp[g] >> (8 * j)) & 0xFFu)], 1u);
        }
    }

    // ---- phase A2: value loads + gathers (latency overlaps hist/scan) ----
    if (full) {
        #pragma unroll
        for (int g = 0; g < 4; ++g) {
            unsigned v = vbase + g * PB + (unsigned)tid;
            iv4 v4 = __builtin_nontemporal_load((const iv4*)vidx + v);
            fv4 w4 = __builtin_nontemporal_load((const fv4*)coeff + v);
            int   vi[4] = {v4.x, v4.y, v4.z, v4.w};
            float wc[4] = {w4.x, w4.y, w4.z, w4.w};
            #pragma unroll
            for (int j = 0; j < 4; ++j) {
                float pv = __builtin_bit_cast(float, (unsigned)probs[vi[j]] << 16);
                unsigned bits = __builtin_bit_cast(unsigned, wc[j] * pv);
                bits += 0x7FFFu + ((bits >> 16) & 1u);     // RNE to bf16
                rw[g * 4 + j] |= bits >> 16;
            }
        }
    } else {
        #pragma unroll
        for (int g = 0; g < 4; ++g) if (gv[g]) {
            unsigned v = vbase + g * PB + (unsigned)tid;
            int4   v4 = ((const int4*)vidx)[v];
            float4 w4 = ((const float4*)coeff)[v];
            int   vi[4] = {v4.x, v4.y, v4.z, v4.w};
            float wc[4] = {w4.x, w4.y, w4.z, w4.w};
            #pragma unroll
            for (int j = 0; j < 4; ++j) {
                float pv = __builtin_bit_cast(float, (unsigned)probs[vi[j]] << 16);
                unsigned bits = __builtin_bit_cast(unsigned, wc[j] * pv);
                bits += 0x7FFFu + ((bits >> 16) & 1u);
                rw[g * 4 + j] |= bits >> 16;
            }
        }
    }
    __syncthreads();   // hist complete

    // ---- wave0: scan + local cursors; wave1: global reservation (parallel) ----
    if (w == 0) {
        unsigned h[8];
        unsigned cnt = 0;
        if (lane < nb) {
            #pragma unroll
            for (int j = 0; j < 8; ++j) { h[j] = hist[(j << 6) + lane]; cnt += h[j]; }
        }
        unsigned sc = cnt;
        #pragma unroll
        for (int d = 1; d < 64; d <<= 1) {
            unsigned t = __shfl_up(sc, d, 64);
            if (lane >= d) sc += t;
        }
        unsigned excl  = sc - cnt;
        unsigned total = __shfl(sc, nb - 1, 64);
        if (lane < nb) {
            bst[lane] = excl;
            unsigned run = excl;
            #pragma unroll
            for (int j = 0; j < 8; ++j) { lcur[(j << 6) + lane] = run; run += h[j]; }
        }
        if (lane == 0) bst[nb] = total;
    } else if (w == 1) {
        if (lane < nb) {
            unsigned cnt2 = 0;
            #pragma unroll
            for (int j = 0; j < 8; ++j) cnt2 += hist[(j << 6) + lane];
            gbs[lane] = cnt2 ? atomicAdd(&cursor[rep * MAXNB + lane], cnt2) : 0u;
        }
    }
    __syncthreads();   // lcur/bst/gbs ready

    // ---- pass B: scatter into sorted LDS ----
    if (full) {
        #pragma unroll
        for (int g = 0; g < 4; ++g)
            #pragma unroll
            for (int j = 0; j < 4; ++j) {
                unsigned b = (bkp[g] >> (8 * j)) & 0xFFu;
                unsigned pos = atomicAdd(&lcur[(w << 6) + b], 1u);
                sorted[pos] = rw[g * 4 + j];
            }
    } else {
        #pragma unroll
        for (int g = 0; g < 4; ++g) if (gv[g]) {
            #pragma unroll
            for (int j = 0; j < 4; ++j) {
                unsigned b = (bkp[g] >> (8 * j)) & 0xFFu;
                unsigned pos = atomicAdd(&lcur[(w << 6) + b], 1u);
                sorted[pos] = rw[g * 4 + j];
            }
        }
    }
    __syncthreads();   // sorted ready

    // ---- copy-out: wave w handles buckets w, w+8, ... into stripe rep ----
    // cached store (not NT): accum re-reads this; let L2 absorb what fits.
    for (int b = w; b < nb; b += 8) {
        unsigned st = bst[b], en = bst[b + 1], gb = gbs[b];
        unsigned* dst = recs + (size_t)(b * NSTRIPE + rep) * scap;
        for (unsigned p = st + (unsigned)lane; p < en; p += 64u) {
            unsigned pos = gb + (p - st);
            if (pos < scap) dst[pos] = sorted[p];
        }
    }
}

// Phase 2: block (b,s) accumulates stripe s of bucket b into LDS via ds_add.
// Two-stream cached uint4 loads (+unroll 2) keep up to 4 independent loads
// in flight per thread — the single-NT-load version had MLP=1 at 8 waves/CU
// and was latency-bound. Then adds the tile into ax with coalesced atomics.
__global__ __launch_bounds__(256) void accum_kernel(
        const unsigned* __restrict__ recs, const unsigned* __restrict__ cursor,
        float* __restrict__ ax, int n_constrs, unsigned scap) {
    __shared__ float acc[R_BKT];
    const int b = blockIdx.x / NSTRIPE;
    const int s = blockIdx.x % NSTRIPE;
    for (int j = threadIdx.x * 4; j < R_BKT; j += blockDim.x * 4)
        *(float4*)(acc + j) = make_float4(0.f, 0.f, 0.f, 0.f);
    __syncthreads();

    unsigned cnt = cursor[s * MAXNB + b];
    if (cnt > scap) cnt = scap;
    const unsigned* base = recs + (size_t)(b * NSTRIPE + s) * scap;

    unsigned c4 = cnt >> 2;
    unsigned h  = c4 >> 1;
    const uv4* b4 = (const uv4*)base;
    #pragma unroll 2
    for (unsigned i = threadIdx.x; i < h; i += blockDim.x) {
        uv4 r0 = b4[i];
        uv4 r1 = b4[h + i];
        unsafeAtomicAdd(&acc[r0.x >> 16], __builtin_bit_cast(float, (r0.x & 0xFFFFu) << 16));
        unsafeAtomicAdd(&acc[r0.y >> 16], __builtin_bit_cast(float, (r0.y & 0xFFFFu) << 16));
        unsafeAtomicAdd(&acc[r0.z >> 16], __builtin_bit_cast(float, (r0.z & 0xFFFFu) << 16));
        unsafeAtomicAdd(&acc[r0.w >> 16], __builtin_bit_cast(float, (r0.w & 0xFFFFu) << 16));
        unsafeAtomicAdd(&acc[r1.x >> 16], __builtin_bit_cast(float, (r1.x & 0xFFFFu) << 16));
        unsafeAtomicAdd(&acc[r1.y >> 16], __builtin_bit_cast(float, (r1.y & 0xFFFFu) << 16));
        unsafeAtomicAdd(&acc[r1.z >> 16], __builtin_bit_cast(float, (r1.z & 0xFFFFu) << 16));
        unsafeAtomicAdd(&acc[r1.w >> 16], __builtin_bit_cast(float, (r1.w & 0xFFFFu) << 16));
    }
    for (unsigned i = (h << 1) + threadIdx.x; i < c4; i += blockDim.x) {
        uv4 r = b4[i];
        unsafeAtomicAdd(&acc[r.x >> 16], __builtin_bit_cast(float, (r.x & 0xFFFFu) << 16));
        unsafeAtomicAdd(&acc[r.y >> 16], __builtin_bit_cast(float, (r.y & 0xFFFFu) << 16));
        unsafeAtomicAdd(&acc[r.z >> 16], __builtin_bit_cast(float, (r.z & 0xFFFFu) << 16));
        unsafeAtomicAdd(&acc[r.w >> 16], __builtin_bit_cast(float, (r.w & 0xFFFFu) << 16));
    }
    for (unsigned i = (c4 << 2) + threadIdx.x; i < cnt; i += blockDim.x) {
        unsigned r = base[i];
        unsafeAtomicAdd(&acc[r >> 16], __builtin_bit_cast(float, (r & 0xFFFFu) << 16));
    }
    __syncthreads();

    const int gb = b * R_BKT;
    for (int j = threadIdx.x; j < R_BKT; j += blockDim.x) {
        int g = gb + j;
        if (g < n_constrs)
            unsafeAtomicAdd(&ax[g], acc[j]);   // coalesced consecutive dwords
    }
}

// Phase 3: violation by sense from ax, mean. (6 MB total traffic.)
__device__ __forceinline__ float viol(float d, int sn) {
    return (sn == 1) ? fmaxf(d, 0.0f)
         : (sn == 2) ? fmaxf(-d, 0.0f)
         : (sn == 3) ? fabsf(d)
         : 0.0f;
}

__global__ void reduce_fast(const float4* __restrict__ ax4,
                            const float4* __restrict__ rhs4,
                            const int4* __restrict__ sense4,
                            float* __restrict__ out,
                            int n4, float inv_n) {
    int i = blockIdx.x * blockDim.x + threadIdx.x;
    float v = 0.0f;
    if (i < n4) {
        float4 a = ax4[i];
        float4 r = rhs4[i];
        int4  sn = sense4[i];
        v = viol(a.x - r.x, sn.x) + viol(a.y - r.y, sn.y)
          + viol(a.z - r.z, sn.z) + viol(a.w - r.w, sn.w);
    }
    #pragma unroll
    for (int off = 32; off > 0; off >>= 1)
        v += __shfl_down(v, off, 64);
    __shared__ float wsum[4];
    int lane = threadIdx.x & 63;
    int wid  = threadIdx.x >> 6;
    if (lane == 0) wsum[wid] = v;
    __syncthreads();
    if (threadIdx.x == 0)
        atomicAdd(out, (wsum[0] + wsum[1] + wsum[2] + wsum[3]) * inv_n);
}

// ======================= fallback path (small ws) =======================

__global__ void init_kernel(const float* __restrict__ pred,
                            float* __restrict__ probs,
                            float* __restrict__ ax,
                            float* __restrict__ out,
                            int n_vars, int n_constrs) {
    int i = blockIdx.x * blockDim.x + threadIdx.x;
    if (i < n_vars) probs[i] = 1.0f / (1.0f + expf(-pred[i]));
    if (i < n_constrs) ax[i] = 0.0f;
    if (i == 0) out[0] = 0.0f;
}

__global__ void scatter_kernel(const int* __restrict__ cidx,
                               const int* __restrict__ vidx,
                               const float* __restrict__ coeff,
                               const float* __restrict__ probs,
                               float* __restrict__ ax,
                               int nnz) {
    int i = blockIdx.x * blockDim.x + threadIdx.x;
    long long base = (long long)i * 4;
    if (base + 3 < (long long)nnz) {
        int4   c = ((const int4*)cidx)[i];
        int4   v = ((const int4*)vidx)[i];
        float4 w = ((const float4*)coeff)[i];
        unsafeAtomicAdd(&ax[c.x], w.x * probs[v.x]);
        unsafeAtomicAdd(&ax[c.y], w.y * probs[v.y]);
        unsafeAtomicAdd(&ax[c.z], w.z * probs[v.z]);
        unsafeAtomicAdd(&ax[c.w], w.w * probs[v.w]);
    } else if (base < (long long)nnz) {
        for (long long k = base; k < (long long)nnz; ++k)
            unsafeAtomicAdd(&ax[cidx[k]], coeff[k] * probs[vidx[k]]);
    }
}

__global__ void reduce_kernel(const float* __restrict__ ax,
                              const float* __restrict__ rhs,
                              const int* __restrict__ sense,
                              float* __restrict__ out,
                              int n_constrs, float inv_n) {
    int i = blockIdx.x * blockDim.x + threadIdx.x;
    float v = 0.0f;
    if (i < n_constrs) {
        float d = ax[i] - rhs[i];
        int s = sense[i];
        v = (s == 1) ? fmaxf(d, 0.0f)
          : (s == 2) ? fmaxf(-d, 0.0f)
          : (s == 3) ? fabsf(d)
          : 0.0f;
    }
    #pragma unroll
    for (int off = 32; off > 0; off >>= 1)
        v += __shfl_down(v, off, 64);
    __shared__ float wsum[4];
    int lane = threadIdx.x & 63;
    int wid  = threadIdx.x >> 6;
    if (lane == 0) wsum[wid] = v;
    __syncthreads();
    if (threadIdx.x == 0)
        atomicAdd(out, (wsum[0] + wsum[1] + wsum[2] + wsum[3]) * inv_n);
}

// ============================== launch ==============================

static inline size_t align16(size_t x) { return (x + 15) & ~(size_t)15; }

extern "C" void kernel_launch(void* const* d_in, const int* in_sizes, int n_in,
                              void* d_out, int out_size, void* d_ws, size_t ws_size,
                              hipStream_t stream) {
    const float* pred  = (const float*)d_in[0];
    const int*   cidx  = (const int*)d_in[1];
    const int*   vidx  = (const int*)d_in[2];
    const float* coeff = (const float*)d_in[3];
    const float* rhs   = (const float*)d_in[4];
    const int*   sense = (const int*)d_in[5];

    const int n_vars    = in_sizes[0];
    const int nnz       = in_sizes[1];
    const int n_constrs = in_sizes[4];
    const int B = 256;
    const float inv_n = 1.0f / (float)n_constrs;

    const int nb = (n_constrs + R_BKT - 1) / R_BKT;
    unsigned scap = (unsigned)(((double)nnz * R_BKT / (double)n_constrs / NSTRIPE)
                               * 1.0625) + 1024;
    scap = (scap + 3u) & ~3u;   // 16B alignment for uint4 loads in accum

    // fast-path workspace layout
    size_t off_probs  = 0;                                      // bf16, n_vars*2
    size_t off_cursor = align16(off_probs + (size_t)n_vars * 2);
    size_t off_recs   = align16(off_cursor + (size_t)MAXNB * NSTRIPE * 4);
    size_t off_ax     = align16(off_recs + (size_t)nb * NSTRIPE * scap * 4);
    size_t need_fast  = off_ax + (size_t)n_constrs * 4;

    bool fast = (ws_size >= need_fast) && (nb <= MAXNB) && ((nnz & 3) == 0)
             && ((n_vars & 3) == 0) && ((n_constrs & 3) == 0);

    if (fast) {
        unsigned short* probs  = (unsigned short*)((char*)d_ws + off_probs);
        unsigned*       cursor = (unsigned*)((char*)d_ws + off_cursor);
        unsigned*       recs   = (unsigned*)((char*)d_ws + off_recs);
        float*          ax     = (float*)((char*)d_ws + off_ax);
        float*          out    = (float*)d_out;

        int n_vars4 = n_vars >> 2;
        int nc4     = n_constrs >> 2;
        int init_n  = n_vars4 > nc4 ? n_vars4 : nc4;
        if (init_n < MAXNB * NSTRIPE) init_n = MAXNB * NSTRIPE;
        init_fast<<<(init_n + B - 1) / B, B, 0, stream>>>(
            (const float4*)pred, (ushort4*)probs, (float4*)ax, cursor, out,
            n_vars4, nc4);

        int nnz4 = nnz >> 2;
        int nblk1 = (nnz4 + (BLK_RECS / 4) - 1) / (BLK_RECS / 4);
        partition_kernel<<<nblk1, PB, 0, stream>>>(
            cidx, vidx, coeff, probs, cursor, recs, nnz4, nb, scap);

        accum_kernel<<<nb * NSTRIPE, B, 0, stream>>>(
            recs, cursor, ax, n_constrs, scap);

        reduce_fast<<<(nc4 + B - 1) / B, B, 0, stream>>>(
            (const float4*)ax, (const float4*)rhs, (const int4*)sense,
            out, nc4, inv_n);
    } else {
        float* probs = (float*)d_ws;
        float* ax    = probs + n_vars;
        float* out   = (float*)d_out;

        int init_n = n_vars > n_constrs ? n_vars : n_constrs;
        init_kernel<<<(init_n + B - 1) / B, B, 0, stream>>>(
            pred, probs, ax, out, n_vars, n_constrs);

        int n_vec_threads = (nnz + 3) / 4;
        scatter_kernel<<<(n_vec_threads + B - 1) / B, B, 0, stream>>>(
            cidx, vidx, coeff, probs, ax, nnz);

        reduce_kernel<<<(n_constrs + B - 1) / B, B, 0, stream>>>(
            ax, rhs, sense, out, n_constrs, inv_n);
    }
}

// Round 10
// 432.243 us; speedup vs baseline: 1.0660x; 1.0153x over previous
//
#include <hip/hip_runtime.h>
#include <math.h>

#define R_LOG2 13
#define R_BKT  8192      // constraints per bucket (32 KB LDS accumulator)
#define NSTRIPE 16       // cursor/recs stripes = accum blocks per bucket
#define MAXNB  64        // max buckets supported by fast path
#define PB     512       // partition block size (8 waves)
#define BLK_RECS 4096    // records per partition block (16 KB sorted[] ->
                         // ~21 KB LDS/block: more resident blocks, shorter
                         // barrier epochs vs 8192's 37.9 KB / 37% occupancy)
#define GRP (BLK_RECS / PB / 4)   // int4 groups per thread = 2

// clang ext-vector types: required by __builtin_nontemporal_load/store
// (HIP_vector_type wrappers are rejected by the builtin).
typedef int      iv4 __attribute__((ext_vector_type(4)));
typedef float    fv4 __attribute__((ext_vector_type(4)));
typedef unsigned uv4 __attribute__((ext_vector_type(4)));

__device__ __forceinline__ unsigned short f32_to_bf16_rne(float f) {
    unsigned b = __builtin_bit_cast(unsigned, f);
    b += 0x7FFFu + ((b >> 16) & 1u);
    return (unsigned short)(b >> 16);
}

// ============================= fast path =============================

// probs = bf16(sigmoid(pred)) — 2 MB table stays L2-resident (measured:
// FETCH 179->125 MB). Zeroes striped cursors (16*64), ax, out.
__global__ void init_fast(const float4* __restrict__ pred4,
                          ushort4* __restrict__ probs4,
                          float4* __restrict__ ax4,
                          unsigned* __restrict__ cursor,
                          float* __restrict__ out,
                          int n_vars4, int nc4) {
    int i = blockIdx.x * blockDim.x + threadIdx.x;
    if (i < n_vars4) {
        float4 p = pred4[i];
        ushort4 q;
        q.x = f32_to_bf16_rne(1.0f / (1.0f + expf(-p.x)));
        q.y = f32_to_bf16_rne(1.0f / (1.0f + expf(-p.y)));
        q.z = f32_to_bf16_rne(1.0f / (1.0f + expf(-p.z)));
        q.w = f32_to_bf16_rne(1.0f / (1.0f + expf(-p.w)));
        probs4[i] = q;
    }
    if (i < nc4) ax4[i] = make_float4(0.f, 0.f, 0.f, 0.f);
    if (i < MAXNB * NSTRIPE) cursor[i] = 0;
    if (i == 0) out[0] = 0.0f;
}

// Phase 1: block counting-sort of 4096 records by bucket (cidx>>13).
// cidx load -> hist (LDS) -> value loads/gathers (latency overlaps
// hist+scan) -> wave0 scan || wave1 global cursor atomic (16-way striped)
// -> scatter -> striped copy-out. recs store cached (accum hits L2 tail).
// Record: {lidx:13 | bf16:16}.
__global__ __launch_bounds__(PB) void partition_kernel(
        const int* __restrict__ cidx, const int* __restrict__ vidx,
        const float* __restrict__ coeff, const unsigned short* __restrict__ probs,
        unsigned* __restrict__ cursor, unsigned* __restrict__ recs,
        int nnz4, int nb, unsigned scap) {
    __shared__ unsigned sorted[BLK_RECS];     // 16 KB
    __shared__ unsigned hist[8 * MAXNB];      // [w*64 + b] 2 KB
    __shared__ unsigned lcur[8 * MAXNB];      // running cursors 2 KB
    __shared__ unsigned bst[MAXNB + 1];       // bucket starts in sorted[]
    __shared__ unsigned gbs[MAXNB];           // reserved global bases

    const int tid  = threadIdx.x;
    const int w    = tid >> 6;                // wave 0..7
    const int lane = tid & 63;
    const int rep  = blockIdx.x & (NSTRIPE - 1);

    hist[tid] = 0;                            // 512 counters, 512 threads

    unsigned rw[4 * GRP];                     // (lidx<<16), later |= bf16
    unsigned bkp[GRP];                        // 4 buckets packed per word
    bool     gv[GRP];
    const unsigned vbase = blockIdx.x * (BLK_RECS / 4);
    const bool full = (vbase + (BLK_RECS / 4)) <= (unsigned)nnz4;

    // ---- phase 0: cidx load, bucket/lidx extraction ----
    if (full) {
        #pragma unroll
        for (int g = 0; g < GRP; ++g) {
            unsigned v = vbase + g * PB + (unsigned)tid;
            iv4 c4 = __builtin_nontemporal_load((const iv4*)cidx + v);
            int cc[4] = {c4.x, c4.y, c4.z, c4.w};
            bkp[g] = ((unsigned)cc[0] >> R_LOG2)
                   | (((unsigned)cc[1] >> R_LOG2) << 8)
                   | (((unsigned)cc[2] >> R_LOG2) << 16)
                   | (((unsigned)cc[3] >> R_LOG2) << 24);
            #pragma unroll
            for (int j = 0; j < 4; ++j)
                rw[g * 4 + j] = (unsigned)(cc[j] & (R_BKT - 1)) << 16;
            gv[g] = true;
        }
    } else {
        #pragma unroll
        for (int g = 0; g < GRP; ++g) {
            unsigned v = vbase + g * PB + (unsigned)tid;
            gv[g] = v < (unsigned)nnz4;
            bkp[g] = 0;
            if (gv[g]) {
                int4 c4 = ((const int4*)cidx)[v];
                int cc[4] = {c4.x, c4.y, c4.z, c4.w};
                bkp[g] = ((unsigned)cc[0] >> R_LOG2)
                       | (((unsigned)cc[1] >> R_LOG2) << 8)
                       | (((unsigned)cc[2] >> R_LOG2) << 16)
                       | (((unsigned)cc[3] >> R_LOG2) << 24);
                #pragma unroll
                for (int j = 0; j < 4; ++j)
                    rw[g * 4 + j] = (unsigned)(cc[j] & (R_BKT - 1)) << 16;
            }
        }
    }
    __syncthreads();   // hist zeros visible

    // ---- phase A: wave-replicated histogram ([w][b] layout) ----
    #pragma unroll
    for (int g = 0; g < GRP; ++g) if (gv[g]) {
        #pragma unroll
        for (int j = 0; j < 4; ++j)
            atomicAdd(&hist[(w << 6) + ((bkp[g] >> (8 * j)) & 0xFFu)], 1u);
    }

    // ---- phase A2: value loads + gathers (latency overlaps hist/scan) ----
    if (full) {
        #pragma unroll
        for (int g = 0; g < GRP; ++g) {
            unsigned v = vbase + g * PB + (unsigned)tid;
            iv4 v4 = __builtin_nontemporal_load((const iv4*)vidx + v);
            fv4 w4 = __builtin_nontemporal_load((const fv4*)coeff + v);
            int   vi[4] = {v4.x, v4.y, v4.z, v4.w};
            float wc[4] = {w4.x, w4.y, w4.z, w4.w};
            #pragma unroll
            for (int j = 0; j < 4; ++j) {
                float pv = __builtin_bit_cast(float, (unsigned)probs[vi[j]] << 16);
                unsigned bits = __builtin_bit_cast(unsigned, wc[j] * pv);
                bits += 0x7FFFu + ((bits >> 16) & 1u);     // RNE to bf16
                rw[g * 4 + j] |= bits >> 16;
            }
        }
    } else {
        #pragma unroll
        for (int g = 0; g < GRP; ++g) if (gv[g]) {
            unsigned v = vbase + g * PB + (unsigned)tid;
            int4   v4 = ((const int4*)vidx)[v];
            float4 w4 = ((const float4*)coeff)[v];
            int   vi[4] = {v4.x, v4.y, v4.z, v4.w};
            float wc[4] = {w4.x, w4.y, w4.z, w4.w};
            #pragma unroll
            for (int j = 0; j < 4; ++j) {
                float pv = __builtin_bit_cast(float, (unsigned)probs[vi[j]] << 16);
                unsigned bits = __builtin_bit_cast(unsigned, wc[j] * pv);
                bits += 0x7FFFu + ((bits >> 16) & 1u);
                rw[g * 4 + j] |= bits >> 16;
            }
        }
    }
    __syncthreads();   // hist complete

    // ---- wave0: scan + local cursors; wave1: global reservation (parallel) ----
    if (w == 0) {
        unsigned h[8];
        unsigned cnt = 0;
        if (lane < nb) {
            #pragma unroll
            for (int j = 0; j < 8; ++j) { h[j] = hist[(j << 6) + lane]; cnt += h[j]; }
        }
        unsigned sc = cnt;
        #pragma unroll
        for (int d = 1; d < 64; d <<= 1) {
            unsigned t = __shfl_up(sc, d, 64);
            if (lane >= d) sc += t;
        }
        unsigned excl  = sc - cnt;
        unsigned total = __shfl(sc, nb - 1, 64);
        if (lane < nb) {
            bst[lane] = excl;
            unsigned run = excl;
            #pragma unroll
            for (int j = 0; j < 8; ++j) { lcur[(j << 6) + lane] = run; run += h[j]; }
        }
        if (lane == 0) bst[nb] = total;
    } else if (w == 1) {
        if (lane < nb) {
            unsigned cnt2 = 0;
            #pragma unroll
            for (int j = 0; j < 8; ++j) cnt2 += hist[(j << 6) + lane];
            gbs[lane] = cnt2 ? atomicAdd(&cursor[rep * MAXNB + lane], cnt2) : 0u;
        }
    }
    __syncthreads();   // lcur/bst/gbs ready

    // ---- pass B: scatter into sorted LDS ----
    #pragma unroll
    for (int g = 0; g < GRP; ++g) if (gv[g]) {
        #pragma unroll
        for (int j = 0; j < 4; ++j) {
            unsigned b = (bkp[g] >> (8 * j)) & 0xFFu;
            unsigned pos = atomicAdd(&lcur[(w << 6) + b], 1u);
            sorted[pos] = rw[g * 4 + j];
        }
    }
    __syncthreads();   // sorted ready

    // ---- copy-out: wave w handles buckets w, w+8, ... into stripe rep ----
    for (int b = w; b < nb; b += 8) {
        unsigned st = bst[b], en = bst[b + 1], gb = gbs[b];
        unsigned* dst = recs + (size_t)(b * NSTRIPE + rep) * scap;
        for (unsigned p = st + (unsigned)lane; p < en; p += 64u) {
            unsigned pos = gb + (p - st);
            if (pos < scap) dst[pos] = sorted[p];
        }
    }
}

// Phase 2: block (b,s) accumulates stripe s of bucket b into LDS via ds_add.
// Two-stream cached uint4 loads keep independent loads in flight, then adds
// the tile into ax with coalesced global atomics.
__global__ __launch_bounds__(256) void accum_kernel(
        const unsigned* __restrict__ recs, const unsigned* __restrict__ cursor,
        float* __restrict__ ax, int n_constrs, unsigned scap) {
    __shared__ float acc[R_BKT];
    const int b = blockIdx.x / NSTRIPE;
    const int s = blockIdx.x % NSTRIPE;
    for (int j = threadIdx.x * 4; j < R_BKT; j += blockDim.x * 4)
        *(float4*)(acc + j) = make_float4(0.f, 0.f, 0.f, 0.f);
    __syncthreads();

    unsigned cnt = cursor[s * MAXNB + b];
    if (cnt > scap) cnt = scap;
    const unsigned* base = recs + (size_t)(b * NSTRIPE + s) * scap;

    unsigned c4 = cnt >> 2;
    unsigned h  = c4 >> 1;
    const uv4* b4 = (const uv4*)base;
    #pragma unroll 2
    for (unsigned i = threadIdx.x; i < h; i += blockDim.x) {
        uv4 r0 = b4[i];
        uv4 r1 = b4[h + i];
        unsafeAtomicAdd(&acc[r0.x >> 16], __builtin_bit_cast(float, (r0.x & 0xFFFFu) << 16));
        unsafeAtomicAdd(&acc[r0.y >> 16], __builtin_bit_cast(float, (r0.y & 0xFFFFu) << 16));
        unsafeAtomicAdd(&acc[r0.z >> 16], __builtin_bit_cast(float, (r0.z & 0xFFFFu) << 16));
        unsafeAtomicAdd(&acc[r0.w >> 16], __builtin_bit_cast(float, (r0.w & 0xFFFFu) << 16));
        unsafeAtomicAdd(&acc[r1.x >> 16], __builtin_bit_cast(float, (r1.x & 0xFFFFu) << 16));
        unsafeAtomicAdd(&acc[r1.y >> 16], __builtin_bit_cast(float, (r1.y & 0xFFFFu) << 16));
        unsafeAtomicAdd(&acc[r1.z >> 16], __builtin_bit_cast(float, (r1.z & 0xFFFFu) << 16));
        unsafeAtomicAdd(&acc[r1.w >> 16], __builtin_bit_cast(float, (r1.w & 0xFFFFu) << 16));
    }
    for (unsigned i = (h << 1) + threadIdx.x; i < c4; i += blockDim.x) {
        uv4 r = b4[i];
        unsafeAtomicAdd(&acc[r.x >> 16], __builtin_bit_cast(float, (r.x & 0xFFFFu) << 16));
        unsafeAtomicAdd(&acc[r.y >> 16], __builtin_bit_cast(float, (r.y & 0xFFFFu) << 16));
        unsafeAtomicAdd(&acc[r.z >> 16], __builtin_bit_cast(float, (r.z & 0xFFFFu) << 16));
        unsafeAtomicAdd(&acc[r.w >> 16], __builtin_bit_cast(float, (r.w & 0xFFFFu) << 16));
    }
    for (unsigned i = (c4 << 2) + threadIdx.x; i < cnt; i += blockDim.x) {
        unsigned r = base[i];
        unsafeAtomicAdd(&acc[r >> 16], __builtin_bit_cast(float, (r & 0xFFFFu) << 16));
    }
    __syncthreads();

    const int gb = b * R_BKT;
    for (int j = threadIdx.x; j < R_BKT; j += blockDim.x) {
        int g = gb + j;
        if (g < n_constrs)
            unsafeAtomicAdd(&ax[g], acc[j]);   // coalesced consecutive dwords
    }
}

// Phase 3: violation by sense from ax, mean. (6 MB total traffic.)
__device__ __forceinline__ float viol(float d, int sn) {
    return (sn == 1) ? fmaxf(d, 0.0f)
         : (sn == 2) ? fmaxf(-d, 0.0f)
         : (sn == 3) ? fabsf(d)
         : 0.0f;
}

__global__ void reduce_fast(const float4* __restrict__ ax4,
                            const float4* __restrict__ rhs4,
                            const int4* __restrict__ sense4,
                            float* __restrict__ out,
                            int n4, float inv_n) {
    int i = blockIdx.x * blockDim.x + threadIdx.x;
    float v = 0.0f;
    if (i < n4) {
        float4 a = ax4[i];
        float4 r = rhs4[i];
        int4  sn = sense4[i];
        v = viol(a.x - r.x, sn.x) + viol(a.y - r.y, sn.y)
          + viol(a.z - r.z, sn.z) + viol(a.w - r.w, sn.w);
    }
    #pragma unroll
    for (int off = 32; off > 0; off >>= 1)
        v += __shfl_down(v, off, 64);
    __shared__ float wsum[4];
    int lane = threadIdx.x & 63;
    int wid  = threadIdx.x >> 6;
    if (lane == 0) wsum[wid] = v;
    __syncthreads();
    if (threadIdx.x == 0)
        atomicAdd(out, (wsum[0] + wsum[1] + wsum[2] + wsum[3]) * inv_n);
}

// ======================= fallback path (small ws) =======================

__global__ void init_kernel(const float* __restrict__ pred,
                            float* __restrict__ probs,
                            float* __restrict__ ax,
                            float* __restrict__ out,
                            int n_vars, int n_constrs) {
    int i = blockIdx.x * blockDim.x + threadIdx.x;
    if (i < n_vars) probs[i] = 1.0f / (1.0f + expf(-pred[i]));
    if (i < n_constrs) ax[i] = 0.0f;
    if (i == 0) out[0] = 0.0f;
}

__global__ void scatter_kernel(const int* __restrict__ cidx,
                               const int* __restrict__ vidx,
                               const float* __restrict__ coeff,
                               const float* __restrict__ probs,
                               float* __restrict__ ax,
                               int nnz) {
    int i = blockIdx.x * blockDim.x + threadIdx.x;
    long long base = (long long)i * 4;
    if (base + 3 < (long long)nnz) {
        int4   c = ((const int4*)cidx)[i];
        int4   v = ((const int4*)vidx)[i];
        float4 w = ((const float4*)coeff)[i];
        unsafeAtomicAdd(&ax[c.x], w.x * probs[v.x]);
        unsafeAtomicAdd(&ax[c.y], w.y * probs[v.y]);
        unsafeAtomicAdd(&ax[c.z], w.z * probs[v.z]);
        unsafeAtomicAdd(&ax[c.w], w.w * probs[v.w]);
    } else if (base < (long long)nnz) {
        for (long long k = base; k < (long long)nnz; ++k)
            unsafeAtomicAdd(&ax[cidx[k]], coeff[k] * probs[vidx[k]]);
    }
}

__global__ void reduce_kernel(const float* __restrict__ ax,
                              const float* __restrict__ rhs,
                              const int* __restrict__ sense,
                              float* __restrict__ out,
                              int n_constrs, float inv_n) {
    int i = blockIdx.x * blockDim.x + threadIdx.x;
    float v = 0.0f;
    if (i < n_constrs) {
        float d = ax[i] - rhs[i];
        int s = sense[i];
        v = (s == 1) ? fmaxf(d, 0.0f)
          : (s == 2) ? fmaxf(-d, 0.0f)
          : (s == 3) ? fabsf(d)
          : 0.0f;
    }
    #pragma unroll
    for (int off = 32; off > 0; off >>= 1)
        v += __shfl_down(v, off, 64);
    __shared__ float wsum[4];
    int lane = threadIdx.x & 63;
    int wid  = threadIdx.x >> 6;
    if (lane == 0) wsum[wid] = v;
    __syncthreads();
    if (threadIdx.x == 0)
        atomicAdd(out, (wsum[0] + wsum[1] + wsum[2] + wsum[3]) * inv_n);
}

// ============================== launch ==============================

static inline size_t align16(size_t x) { return (x + 15) & ~(size_t)15; }

extern "C" void kernel_launch(void* const* d_in, const int* in_sizes, int n_in,
                              void* d_out, int out_size, void* d_ws, size_t ws_size,
                              hipStream_t stream) {
    const float* pred  = (const float*)d_in[0];
    const int*   cidx  = (const int*)d_in[1];
    const int*   vidx  = (const int*)d_in[2];
    const float* coeff = (const float*)d_in[3];
    const float* rhs   = (const float*)d_in[4];
    const int*   sense = (const int*)d_in[5];

    const int n_vars    = in_sizes[0];
    const int nnz       = in_sizes[1];
    const int n_constrs = in_sizes[4];
    const int B = 256;
    const float inv_n = 1.0f / (float)n_constrs;

    const int nb = (n_constrs + R_BKT - 1) / R_BKT;
    unsigned scap = (unsigned)(((double)nnz * R_BKT / (double)n_constrs / NSTRIPE)
                               * 1.0625) + 1024;
    scap = (scap + 3u) & ~3u;   // 16B alignment for uint4 loads in accum

    // fast-path workspace layout
    size_t off_probs  = 0;                                      // bf16, n_vars*2
    size_t off_cursor = align16(off_probs + (size_t)n_vars * 2);
    size_t off_recs   = align16(off_cursor + (size_t)MAXNB * NSTRIPE * 4);
    size_t off_ax     = align16(off_recs + (size_t)nb * NSTRIPE * scap * 4);
    size_t need_fast  = off_ax + (size_t)n_constrs * 4;

    bool fast = (ws_size >= need_fast) && (nb <= MAXNB) && ((nnz & 3) == 0)
             && ((n_vars & 3) == 0) && ((n_constrs & 3) == 0);

    if (fast) {
        unsigned short* probs  = (unsigned short*)((char*)d_ws + off_probs);
        unsigned*       cursor = (unsigned*)((char*)d_ws + off_cursor);
        unsigned*       recs   = (unsigned*)((char*)d_ws + off_recs);
        float*          ax     = (float*)((char*)d_ws + off_ax);
        float*          out    = (float*)d_out;

        int n_vars4 = n_vars >> 2;
        int nc4     = n_constrs >> 2;
        int init_n  = n_vars4 > nc4 ? n_vars4 : nc4;
        if (init_n < MAXNB * NSTRIPE) init_n = MAXNB * NSTRIPE;
        init_fast<<<(init_n + B - 1) / B, B, 0, stream>>>(
            (const float4*)pred, (ushort4*)probs, (float4*)ax, cursor, out,
            n_vars4, nc4);

        int nnz4 = nnz >> 2;
        int nblk1 = (nnz4 + (BLK_RECS / 4) - 1) / (BLK_RECS / 4);
        partition_kernel<<<nblk1, PB, 0, stream>>>(
            cidx, vidx, coeff, probs, cursor, recs, nnz4, nb, scap);

        accum_kernel<<<nb * NSTRIPE, B, 0, stream>>>(
            recs, cursor, ax, n_constrs, scap);

        reduce_fast<<<(nc4 + B - 1) / B, B, 0, stream>>>(
            (const float4*)ax, (const float4*)rhs, (const int4*)sense,
            out, nc4, inv_n);
    } else {
        float* probs = (float*)d_ws;
        float* ax    = probs + n_vars;
        float* out   = (float*)d_out;

        int init_n = n_vars > n_constrs ? n_vars : n_constrs;
        init_kernel<<<(init_n + B - 1) / B, B, 0, stream>>>(
            pred, probs, ax, out, n_vars, n_constrs);

        int n_vec_threads = (nnz + 3) / 4;
        scatter_kernel<<<(n_vec_threads + B - 1) / B, B, 0, stream>>>(
            cidx, vidx, coeff, probs, ax, nnz);

        reduce_kernel<<<(n_constrs + B - 1) / B, B, 0, stream>>>(
            ax, rhs, sense, out, n_constrs, inv_n);
    }
}